// Round 10
// baseline (274.505 us; speedup 1.0000x reference)
//
#include <hip/hip_runtime.h>

#define NN 2048
#define PITCH 72  // u16 elems per LDS row: 144B -> 16B-aligned rows

typedef __attribute__((ext_vector_type(8))) _Float16 half8;  // 8 fp16 = 4 VGPRs (MFMA A/B frag)
typedef __attribute__((ext_vector_type(4))) float floatx4;   // MFMA C/D frag

static_assert(sizeof(half8) == 16, "");

#define MRINIT -3.0e38f

__device__ __forceinline__ unsigned short f2h(float f) {
    union { _Float16 h; unsigned short u; } v;
    v.h = (_Float16)f;  // RNE
    return v.u;
}
__device__ __forceinline__ float h2f(unsigned short u) {
    union { unsigned short u; _Float16 h; } v;
    v.u = u;
    return (float)v.h;
}
__device__ __forceinline__ unsigned int pk2h(float a, float b) {  // v_cvt_pkrtz_f16_f32
    union { __fp16 __attribute__((ext_vector_type(2))) h; unsigned int u; } v;
    v.h = __builtin_amdgcn_cvt_pkrtz(a, b);
    return v.u;
}
// barrier that does NOT drain vmcnt: LDS-visibility only (lgkmcnt(0)); prefetch
// global loads stay in flight across it (hipBLASLt-style).
__device__ __forceinline__ void barrier_lds_only() {
    __asm__ __volatile__("" ::: "memory");
    __builtin_amdgcn_s_waitcnt(0xC07F);  // vmcnt=63, expcnt=7, lgkmcnt=0
    __builtin_amdgcn_s_barrier();
    __asm__ __volatile__("" ::: "memory");
}

// ---------- mask = (graph + I) > 0, packed to bits: mbits[i*64 + w] bit b = mask[i][w*32+b] ----------
__global__ __launch_bounds__(256) void mask_kernel(const int* __restrict__ graph,
                                                   unsigned int* __restrict__ mbits) {
    const int t = threadIdx.x;
    const int lane = t & 63;
    const int W = (blockIdx.x << 2) + (t >> 6);  // wave id, 0..65535
    const int i = W >> 5;                        // row 0..2047
    const int cb = W & 31;                       // 64-col chunk
    const int j = (cb << 6) + lane;
    const int g = graph[(size_t)i * NN + j];
    const unsigned long long bal = __ballot((g > 0) || (i == j));
    if (lane == 0)  mbits[(i << 6) + (cb << 1)]     = (unsigned int)bal;
    if (lane == 32) mbits[(i << 6) + (cb << 1) + 1] = (unsigned int)(bal >> 32);
}

// ---------- h[b,h,n,d] = sum_c x[b,n,c] * Wh[h,d,c]  (fp32 in, fp16 out) ----------
__global__ __launch_bounds__(256) void proj_kernel(const float* __restrict__ x,
                                                   const float* __restrict__ Wh,
                                                   unsigned short* __restrict__ hout) {
    __shared__ float xs[16 * 64];   // 4 KB
    __shared__ float wsh[64 * 65];  // 16.25 KB, pad 65 -> conflict-free
    const int t = threadIdx.x;
    const int pair = blockIdx.x >> 7;  // b*4 + hh
    const int nt = blockIdx.x & 127;
    const int n0 = nt << 4;
    const int b = pair >> 2;
    const int hh = pair & 3;
    const float* xb = x + (((size_t)b * NN + n0) << 6);
    for (int i = t; i < 1024; i += 256) xs[i] = xb[i];
    const float* wb = Wh + (hh << 12);
    for (int i = t; i < 4096; i += 256) wsh[(i >> 6) * 65 + (i & 63)] = wb[i];
    __syncthreads();
    const int d = t & 63;
    const int q = t >> 6;
    float a0 = 0.f, a1 = 0.f, a2 = 0.f, a3 = 0.f;
    for (int c = 0; c < 64; ++c) {
        const float w = wsh[d * 65 + c];
        a0 += xs[(((q << 2) + 0) << 6) + c] * w;
        a1 += xs[(((q << 2) + 1) << 6) + c] * w;
        a2 += xs[(((q << 2) + 2) << 6) + c] * w;
        a3 += xs[(((q << 2) + 3) << 6) + c] * w;
    }
    unsigned short* ho = hout + (((size_t)pair * NN + n0 + (q << 2)) << 6) + d;
    ho[0]   = f2h(a0);
    ho[64]  = f2h(a1);
    ho[128] = f2h(a2);
    ho[192] = f2h(a3);
}

// ---------- fused GAT layer: Out[mat,n,:] = softmax_mask(H H^T)[n,:] @ H + bias ----------
// 4 waves/block; QG q-groups of 16 rows/wave; K-tiles of 64; flash softmax (exp2 domain).
// QK A-frags: DIRECT from global, register-prefetched ONE ITERATION ahead (latency hidden
// by the full compute phase; loads stay in flight across the lgkm-only barrier).
// V (transposed, swizzled) double-buffered in LDS; Ps per-wave; ONE barrier per iter,
// placed between Ps writes and PV reads (orders Kts staging AND Ps).
// OUTMODE 0: fp16 out, leaky pre-applied. OUTMODE 1: fused leaky+LayerNorm, fp32 out.
template <int QG, int OUTMODE>
__global__ __launch_bounds__(256) void gat_flash(const unsigned short* __restrict__ Hm,
                                                 const unsigned int* __restrict__ mbits,
                                                 const float* __restrict__ bias,
                                                 const int bias_mod,
                                                 const float* __restrict__ gamma,
                                                 const float* __restrict__ beta,
                                                 void* __restrict__ OutP) {
    __shared__ unsigned short Kts[2][64 * PITCH];        // transposed K/V tile [d][j], swizzled, dbuf
    __shared__ unsigned short Ps[4 * QG * 16 * PITCH];   // per-(wave,group) P [m][j], swizzled

    const int t = threadIdx.x;
    const int wave = t >> 6;
    const int lane = t & 63;
    const int quad = lane >> 4;
    const int m = lane & 15;

    const int qtbits = (QG == 2) ? 4 : 5;                // qtiles = 16 or 32
    const int mat = blockIdx.x >> qtbits;
    const int qt = blockIdx.x & ((1 << qtbits) - 1);
    const int q0 = qt << ((QG == 2) ? 7 : 6);

    const unsigned short* Hb = Hm + ((size_t)mat << 17);  // mat * 2048 * 64
    const int wbase = q0 + wave * (16 * QG);

    // Q B-frags per group, loaded once; scaled by log2(e) -> exp2 domain (exact)
    const _Float16 LOG2E = (_Float16)1.44269504f;
    half8 bq0[QG], bq1[QG];
    int gq[QG];
#pragma unroll
    for (int g = 0; g < QG; ++g) {
        gq[g] = wbase + (g << 4) + m;
        bq0[g] = *(const half8*)(Hb + (gq[g] << 6) + (quad << 3)) * LOG2E;
        bq1[g] = *(const half8*)(Hb + (gq[g] << 6) + 32 + (quad << 3)) * LOG2E;
    }

    const int boff = (mat % bias_mod) << 6;
    const float bv0 = bias[boff + m];
    const float bv1 = bias[boff + 16 + m];
    const float bv2 = bias[boff + 32 + m];
    const float bv3 = bias[boff + 48 + m];

    // staging assignment: thread -> rows {2p, 2p+1}, d-chunk cc
    const int p = t >> 3;
    const int cc = t & 7;
    const int jch = p >> 2;         // j-chunk for transposed writes
    const int jo = (p & 3) << 1;    // u16 offset within 8-elem chunk

    float mr[QG], lr[QG];
    floatx4 O[QG][4];
#pragma unroll
    for (int g = 0; g < QG; ++g) {
        mr[g] = MRINIT;
        lr[g] = 0.f;
#pragma unroll
        for (int nt = 0; nt < 4; ++nt) O[g][nt] = floatx4{0.f, 0.f, 0.f, 0.f};
    }

    const int msw = m & 7;
    int psb[QG];
#pragma unroll
    for (int g = 0; g < QG; ++g) psb[g] = (wave * QG + g) * 1152 + m * PITCH;

    // A-frag global base for this lane: row (16jt+m), cols 8*quad..+8
    const unsigned short* abase = Hb + (m << 6) + (quad << 3);

    // ---- prefetch tile 0: staging regs + A-frag regs ----
    const unsigned short* kg0 = Hb + ((p << 1) << 6) + (cc << 3);
    half8 ra = *(const half8*)(kg0);
    half8 rb = *(const half8*)(kg0 + 64);
    half8 af0[4], af1[4];
#pragma unroll
    for (int jt = 0; jt < 4; ++jt) {
        af0[jt] = *(const half8*)(abase + (jt << 10));
        af1[jt] = *(const half8*)(abase + (jt << 10) + 32);
    }

    for (int kt = 0; kt < 32; ++kt) {
        unsigned short* KT = Kts[kt & 1];
        // ---- write prefetched staging tile kt (VGPR->LDS, v_perm pack, swizzled) ----
        union { half8 v; unsigned int u[4]; } kaU, kbU;
        kaU.v = ra;
        kbU.v = rb;
#pragma unroll
        for (int c = 0; c < 4; ++c) {
            const unsigned int ua = kaU.u[c];  // halves d0=8cc+2c (lo16), d0+1 (hi16), j=2p
            const unsigned int ub = kbU.u[c];  // same d's, j=2p+1
            const unsigned int lo = __builtin_amdgcn_perm(ub, ua, 0x05040100);  // row d0
            const unsigned int hi = __builtin_amdgcn_perm(ub, ua, 0x07060302);  // row d0+1
            const int d0 = (cc << 3) + (c << 1);
            const int pos = ((jch ^ cc) << 3) + jo;  // swizzle: 8-way alias -> 2-way
            *(unsigned int*)(&KT[d0 * PITCH + pos]) = lo;
            *(unsigned int*)(&KT[(d0 + 1) * PITCH + pos]) = hi;
        }
        const int ktn = (kt + 1) & 31;
        // ---- issue staging prefetch for tile kt+1 (in flight across the barrier) ----
        const unsigned short* kgn = Hb + (((ktn << 6) + (p << 1)) << 6) + (cc << 3);
        ra = *(const half8*)(kgn);
        rb = *(const half8*)(kgn + 64);

        // ---- S^T = K * Q^T : A-frags from registers (prefetched last iter), no LDS dep ----
        floatx4 a[QG][4];
#pragma unroll
        for (int jt = 0; jt < 4; ++jt) {
#pragma unroll
            for (int g = 0; g < QG; ++g) {
                floatx4 z = {0.f, 0.f, 0.f, 0.f};
                z = __builtin_amdgcn_mfma_f32_16x16x32_f16(af0[jt], bq0[g], z, 0, 0, 0);
                z = __builtin_amdgcn_mfma_f32_16x16x32_f16(af1[jt], bq1[g], z, 0, 0, 0);
                a[g][jt] = z;
            }
        }
        // ---- issue A-frag prefetch for tile kt+1 (covered by softmax+barrier+PV) ----
        const unsigned short* an = abase + (ktn << 12);
#pragma unroll
        for (int jt = 0; jt < 4; ++jt) {
            af0[jt] = *(const half8*)(an + (jt << 10));
            af1[jt] = *(const half8*)(an + (jt << 10) + 32);
        }

        // ---- per group: mask, online softmax, Ps write, O rescale ----
#pragma unroll
        for (int g = 0; g < QG; ++g) {
            const int mrow = gq[g] << 6;
            const unsigned int w0 = mbits[mrow + (kt << 1)];
            const unsigned int w1 = mbits[mrow + (kt << 1) + 1];

            float tmx = MRINIT;
#pragma unroll
            for (int jt = 0; jt < 4; ++jt) {
                const unsigned int wv = (jt < 2) ? w0 : w1;
                const unsigned int bits = (wv >> (((jt & 1) << 4) + (quad << 2))) & 0xFu;
#pragma unroll
                for (int reg = 0; reg < 4; ++reg) {
                    const float v = ((bits >> reg) & 1u) ? a[g][jt][reg] : MRINIT;
                    a[g][jt][reg] = v;  // masked -> exp2(MRINIT - mnew) == 0
                    tmx = fmaxf(tmx, v);
                }
            }
            tmx = fmaxf(tmx, __shfl_xor(tmx, 16));
            tmx = fmaxf(tmx, __shfl_xor(tmx, 32));
            const float mnew = fmaxf(mr[g], tmx);
            const float alpha = __builtin_amdgcn_exp2f(mr[g] - mnew);
            const bool need = __any(mnew > mr[g]);

            float psum = 0.f;
#pragma unroll
            for (int jt = 0; jt < 4; ++jt) {
                const float p0 = __builtin_amdgcn_exp2f(a[g][jt][0] - mnew);
                const float p1 = __builtin_amdgcn_exp2f(a[g][jt][1] - mnew);
                const float p2 = __builtin_amdgcn_exp2f(a[g][jt][2] - mnew);
                const float p3 = __builtin_amdgcn_exp2f(a[g][jt][3] - mnew);
                psum += (p0 + p1) + (p2 + p3);
                const int ch = (jt << 1) + (quad >> 1);  // j>>3 for j = 16jt+4quad+reg
                *(uint2*)(&Ps[psb[g] + ((ch ^ msw) << 3) + ((quad & 1) << 2)]) =
                    make_uint2(pk2h(p0, p1), pk2h(p2, p3));
            }
            psum += __shfl_xor(psum, 16);
            psum += __shfl_xor(psum, 32);
            lr[g] = lr[g] * alpha + psum;
            mr[g] = mnew;

            if (need) {
                const float aO0 = __shfl(alpha, (quad << 2) + 0);
                const float aO1 = __shfl(alpha, (quad << 2) + 1);
                const float aO2 = __shfl(alpha, (quad << 2) + 2);
                const float aO3 = __shfl(alpha, (quad << 2) + 3);
#pragma unroll
                for (int nt = 0; nt < 4; ++nt) {
                    O[g][nt][0] *= aO0;
                    O[g][nt][1] *= aO1;
                    O[g][nt][2] *= aO2;
                    O[g][nt][3] *= aO3;
                }
            }
        }

        // one barrier per iter: orders (a) all waves' Kts staging of tile kt before PV
        // reads, (b) this wave's Ps writes before its pa reads. Prefetch vmcnt untouched.
        barrier_lds_only();

        // ---- O += P * V : A = P[g] (swizzled), B = V[j][d] from swizzled Kts (shared) ----
        half8 pa0[QG], pa1[QG];
#pragma unroll
        for (int g = 0; g < QG; ++g) {
            pa0[g] = *(const half8*)(&Ps[psb[g] + ((quad ^ msw) << 3)]);
            pa1[g] = *(const half8*)(&Ps[psb[g] + (((4 + quad) ^ msw) << 3)]);
        }
#pragma unroll
        for (int nt = 0; nt < 4; ++nt) {
            const int d = (nt << 4) + m;
            const int sw = (d >> 3) & 7;
            const half8 v0 = *(const half8*)(&KT[d * PITCH + ((quad ^ sw) << 3)]);
            const half8 v1 = *(const half8*)(&KT[d * PITCH + (((4 + quad) ^ sw) << 3)]);
#pragma unroll
            for (int g = 0; g < QG; ++g) {
                O[g][nt] = __builtin_amdgcn_mfma_f32_16x16x32_f16(pa0[g], v0, O[g][nt], 0, 0, 0);
                O[g][nt] = __builtin_amdgcn_mfma_f32_16x16x32_f16(pa1[g], v1, O[g][nt], 0, 0, 0);
            }
        }
    }

    // ---- epilogue per group: 1/l, +bias, leaky; fp16 store or fused LayerNorm fp32 ----
    float g0, g1, g2, g3, be0, be1, be2, be3;
    if (OUTMODE == 1) {
        g0 = gamma[m]; g1 = gamma[16 + m]; g2 = gamma[32 + m]; g3 = gamma[48 + m];
        be0 = beta[m]; be1 = beta[16 + m]; be2 = beta[32 + m]; be3 = beta[48 + m];
    }
#pragma unroll
    for (int g = 0; g < QG; ++g) {
        const float l0 = 1.f / __shfl(lr[g], (quad << 2) + 0);
        const float l1 = 1.f / __shfl(lr[g], (quad << 2) + 1);
        const float l2 = 1.f / __shfl(lr[g], (quad << 2) + 2);
        const float l3 = 1.f / __shfl(lr[g], (quad << 2) + 3);
        const size_t obase = (((size_t)mat * NN + wbase + (g << 4) + (quad << 2)) << 6) + m;
#pragma unroll
        for (int reg = 0; reg < 4; ++reg) {
            const float li = (reg == 0) ? l0 : (reg == 1) ? l1 : (reg == 2) ? l2 : l3;
            float z0 = O[g][0][reg] * li + bv0;
            float z1 = O[g][1][reg] * li + bv1;
            float z2 = O[g][2][reg] * li + bv2;
            float z3 = O[g][3][reg] * li + bv3;
            z0 = (z0 > 0.f) ? z0 : 0.2f * z0;  // leaky_relu(0.2), both layers
            z1 = (z1 > 0.f) ? z1 : 0.2f * z1;
            z2 = (z2 > 0.f) ? z2 : 0.2f * z2;
            z3 = (z3 > 0.f) ? z3 : 0.2f * z3;
            if (OUTMODE == 0) {
                unsigned short* op = (unsigned short*)OutP + obase + ((size_t)reg << 6);
                op[0] = f2h(z0); op[16] = f2h(z1); op[32] = f2h(z2); op[48] = f2h(z3);
            } else {
                float s = ((z0 + z1) + (z2 + z3));
                float sq = ((z0 * z0 + z1 * z1) + (z2 * z2 + z3 * z3));
#pragma unroll
                for (int off = 1; off < 16; off <<= 1) {
                    s += __shfl_xor(s, off);
                    sq += __shfl_xor(sq, off);
                }
                const float mu = s * 0.015625f;
                float var = sq * 0.015625f - mu * mu;
                var = fmaxf(var, 0.f);
                const float rstd = rsqrtf(var + 1e-5f);
                float* op = (float*)OutP + obase + ((size_t)reg << 6);
                op[0]  = (z0 - mu) * rstd * g0 + be0;
                op[16] = (z1 - mu) * rstd * g1 + be1;
                op[32] = (z2 - mu) * rstd * g2 + be2;
                op[48] = (z3 - mu) * rstd * g3 + be3;
            }
        }
    }
}

// ---------- h2[b,n,d] = sum_k z[b,n,k] * Wo[d,k];  z = oh (leaky pre-applied), head-major ----------
__global__ __launch_bounds__(256) void mix_kernel(const unsigned short* __restrict__ oh,
                                                  const float* __restrict__ Wo,
                                                  unsigned short* __restrict__ h2) {
    __shared__ float zs[16 * 256];           // 16 KB
    __shared__ unsigned short wsm[64 * 258]; // ~33 KB (fp16 bits)
    const int t = threadIdx.x;
    const int b = blockIdx.x >> 7;
    const int nt = blockIdx.x & 127;
    const int n0 = nt << 4;
    for (int i = t; i < 16384; i += 256) wsm[(i >> 8) * 258 + (i & 255)] = f2h(Wo[i]);
    for (int i = t; i < 4096; i += 256) {
        const int r = i >> 8;
        const int k = i & 255;
        zs[(r << 8) + k] = h2f(oh[((((size_t)b << 2) + (k >> 6)) * NN + n0 + r) * 64 + (k & 63)]);
    }
    __syncthreads();
    const int d = t & 63;
    const int q = t >> 6;
    float a0 = 0.f, a1 = 0.f, a2 = 0.f, a3 = 0.f;
    for (int k = 0; k < 256; ++k) {
        const float w = h2f(wsm[d * 258 + k]);
        a0 += zs[(((q << 2) + 0) << 8) + k] * w;
        a1 += zs[(((q << 2) + 1) << 8) + k] * w;
        a2 += zs[(((q << 2) + 2) << 8) + k] * w;
        a3 += zs[(((q << 2) + 3) << 8) + k] * w;
    }
    unsigned short* hp = h2 + (((size_t)b * NN + n0 + (q << 2)) << 6) + d;
    hp[0]   = f2h(a0);
    hp[64]  = f2h(a1);
    hp[128] = f2h(a2);
    hp[192] = f2h(a3);
}

extern "C" void kernel_launch(void* const* d_in, const int* in_sizes, int n_in,
                              void* d_out, int out_size, void* d_ws, size_t ws_size,
                              hipStream_t stream) {
    const float* x     = (const float*)d_in[0];
    const int*   graph = (const int*)d_in[1];
    const float* Wh    = (const float*)d_in[2];
    const float* bh    = (const float*)d_in[3];
    const float* Wo    = (const float*)d_in[4];
    const float* bo    = (const float*)d_in[5];
    const float* gamma = (const float*)d_in[6];
    const float* beta  = (const float*)d_in[7];
    float* out = (float*)d_out;

    // ---- workspace layout (16.5 MB, with reuse) ----
    char* ws = (char*)d_ws;
    unsigned int* mbits = (unsigned int*)ws;                 // [0, 0.5MB)
    unsigned short* h   = (unsigned short*)(ws + 0x080000);  // fp16 [32,2048,64], dead after gat1
    unsigned short* oh  = (unsigned short*)(ws + 0x880000);  // fp16 [32,2048,64], dead after mix
    unsigned short* h2  = (unsigned short*)(ws + 0x080000);  // overlays h

    mask_kernel<<<16384, 256, 0, stream>>>(graph, mbits);
    proj_kernel<<<4096, 256, 0, stream>>>(x, Wh, h);
    gat_flash<2, 0><<<512, 256, 0, stream>>>(h, mbits, bh, 4, nullptr, nullptr, oh);   // layer 1
    mix_kernel<<<1024, 256, 0, stream>>>(oh, Wo, h2);
    gat_flash<1, 1><<<256, 256, 0, stream>>>(h2, mbits, bo, 1, gamma, beta, out);      // layer 2 + LN
}

// Round 11
// 235.261 us; speedup vs baseline: 1.1668x; 1.1668x over previous
//
#include <hip/hip_runtime.h>

#define NN 2048
#define PITCH 72   // u16 elems per LDS row (gat): 144B -> 16B-aligned rows
#define MPITCH 264 // u16 elems per LDS row (mix): 528B, bank-shift 4/row

typedef __attribute__((ext_vector_type(8))) _Float16 half8;  // 8 fp16 = 4 VGPRs (MFMA A/B frag)
typedef __attribute__((ext_vector_type(4))) float floatx4;   // MFMA C/D frag

static_assert(sizeof(half8) == 16, "");

#define MRINIT -3.0e38f

__device__ __forceinline__ unsigned short f2h(float f) {
    union { _Float16 h; unsigned short u; } v;
    v.h = (_Float16)f;  // RNE
    return v.u;
}
__device__ __forceinline__ float h2f(unsigned short u) {
    union { unsigned short u; _Float16 h; } v;
    v.u = u;
    return (float)v.h;
}
__device__ __forceinline__ unsigned int pk2h(float a, float b) {  // v_cvt_pkrtz_f16_f32
    union { __fp16 __attribute__((ext_vector_type(2))) h; unsigned int u; } v;
    v.h = __builtin_amdgcn_cvt_pkrtz(a, b);
    return v.u;
}
// barrier that does NOT drain vmcnt: LDS-visibility only; prefetch loads stay in flight.
__device__ __forceinline__ void barrier_lds_only() {
    __asm__ __volatile__("" ::: "memory");
    __builtin_amdgcn_s_waitcnt(0xC07F);  // vmcnt=63, expcnt=7, lgkmcnt=0
    __builtin_amdgcn_s_barrier();
    __asm__ __volatile__("" ::: "memory");
}

// ---------- mask = (graph + I) > 0, packed to bits ----------
__global__ __launch_bounds__(256) void mask_kernel(const int* __restrict__ graph,
                                                   unsigned int* __restrict__ mbits) {
    const int t = threadIdx.x;
    const int lane = t & 63;
    const int W = (blockIdx.x << 2) + (t >> 6);
    const int i = W >> 5;
    const int cb = W & 31;
    const int j = (cb << 6) + lane;
    const int g = graph[(size_t)i * NN + j];
    const unsigned long long bal = __ballot((g > 0) || (i == j));
    if (lane == 0)  mbits[(i << 6) + (cb << 1)]     = (unsigned int)bal;
    if (lane == 32) mbits[(i << 6) + (cb << 1) + 1] = (unsigned int)(bal >> 32);
}

// ---------- h[b,h,n,d] = sum_c x[b,n,c] * Wh[h,d,c]  (fp32 in, fp16 out) ----------
__global__ __launch_bounds__(256) void proj_kernel(const float* __restrict__ x,
                                                   const float* __restrict__ Wh,
                                                   unsigned short* __restrict__ hout) {
    __shared__ float xs[16 * 64];
    __shared__ float wsh[64 * 65];
    const int t = threadIdx.x;
    const int pair = blockIdx.x >> 7;
    const int nt = blockIdx.x & 127;
    const int n0 = nt << 4;
    const int b = pair >> 2;
    const int hh = pair & 3;
    const float* xb = x + (((size_t)b * NN + n0) << 6);
    for (int i = t; i < 1024; i += 256) xs[i] = xb[i];
    const float* wb = Wh + (hh << 12);
    for (int i = t; i < 4096; i += 256) wsh[(i >> 6) * 65 + (i & 63)] = wb[i];
    __syncthreads();
    const int d = t & 63;
    const int q = t >> 6;
    float a0 = 0.f, a1 = 0.f, a2 = 0.f, a3 = 0.f;
    for (int c = 0; c < 64; ++c) {
        const float w = wsh[d * 65 + c];
        a0 += xs[(((q << 2) + 0) << 6) + c] * w;
        a1 += xs[(((q << 2) + 1) << 6) + c] * w;
        a2 += xs[(((q << 2) + 2) << 6) + c] * w;
        a3 += xs[(((q << 2) + 3) << 6) + c] * w;
    }
    unsigned short* ho = hout + (((size_t)pair * NN + n0 + (q << 2)) << 6) + d;
    ho[0]   = f2h(a0);
    ho[64]  = f2h(a1);
    ho[128] = f2h(a2);
    ho[192] = f2h(a3);
}

// ---------- fused GAT layer (r9 core) ----------
// OUTMODE 0: fp16 out, leaky fused. OUTMODE 1: fused leaky+LN fp32. OUTMODE 2: split-K
// partials (un-normalized O fp32 + per-row (m,l)); grid carries a split bit; 16 K-tiles.
template <int QG, int OUTMODE>
__global__ __launch_bounds__(256) void gat_flash(const unsigned short* __restrict__ Hm,
                                                 const unsigned int* __restrict__ mbits,
                                                 const float* __restrict__ bias,
                                                 const int bias_mod,
                                                 const float* __restrict__ gamma,
                                                 const float* __restrict__ beta,
                                                 void* __restrict__ OutP,
                                                 float2* __restrict__ mlP) {
    __shared__ unsigned short Ks[2][64 * PITCH];
    __shared__ unsigned short Kts[2][64 * PITCH];
    __shared__ unsigned short Ps[4 * QG * 16 * PITCH];

    const int t = threadIdx.x;
    const int wave = t >> 6;
    const int lane = t & 63;
    const int quad = lane >> 4;
    const int m = lane & 15;

    const int qtbits = (QG == 2) ? 4 : 5;
    const int bid = blockIdx.x;
    const int qt = bid & ((1 << qtbits) - 1);
    const int split = (OUTMODE == 2) ? ((bid >> qtbits) & 1) : 0;
    const int mat = bid >> (qtbits + ((OUTMODE == 2) ? 1 : 0));
    const int q0 = qt << ((QG == 2) ? 7 : 6);
    const int nkt = (OUTMODE == 2) ? 16 : 32;
    const int kt0 = split * nkt;

    const unsigned short* Hb = Hm + ((size_t)mat << 17);
    const int wbase = q0 + wave * (16 * QG);

    const _Float16 LOG2E = (_Float16)1.44269504f;
    half8 bq0[QG], bq1[QG];
    int gq[QG];
#pragma unroll
    for (int g = 0; g < QG; ++g) {
        gq[g] = wbase + (g << 4) + m;
        bq0[g] = *(const half8*)(Hb + (gq[g] << 6) + (quad << 3)) * LOG2E;
        bq1[g] = *(const half8*)(Hb + (gq[g] << 6) + 32 + (quad << 3)) * LOG2E;
    }

    const int boff = (mat % bias_mod) << 6;
    const float bv0 = bias[boff + m];
    const float bv1 = bias[boff + 16 + m];
    const float bv2 = bias[boff + 32 + m];
    const float bv3 = bias[boff + 48 + m];

    const int p = t >> 3;
    const int cc = t & 7;
    const int jch = p >> 2;
    const int jo = (p & 3) << 1;

    float mr[QG], lr[QG];
    floatx4 O[QG][4];
#pragma unroll
    for (int g = 0; g < QG; ++g) {
        mr[g] = MRINIT;
        lr[g] = 0.f;
#pragma unroll
        for (int nt = 0; nt < 4; ++nt) O[g][nt] = floatx4{0.f, 0.f, 0.f, 0.f};
    }

    const int msw = m & 7;
    int psb[QG];
#pragma unroll
    for (int g = 0; g < QG; ++g) psb[g] = (wave * QG + g) * 1152 + m * PITCH;

    // ---- prefetch tile kt0 into registers ----
    const unsigned short* kg0 = Hb + (((kt0 << 6) + (p << 1)) << 6) + (cc << 3);
    half8 ra = *(const half8*)(kg0);
    half8 rb = *(const half8*)(kg0 + 64);

    for (int it = 0; it < nkt; ++it) {
        const int kt = kt0 + it;
        unsigned short* KS = Ks[it & 1];
        unsigned short* KT = Kts[it & 1];
        // ---- write prefetched tile kt (VGPR->LDS); vmcnt wait lands here, one iter late ----
        *(half8*)(&KS[(p << 1) * PITCH + (cc << 3)]) = ra;
        *(half8*)(&KS[((p << 1) + 1) * PITCH + (cc << 3)]) = rb;
        union { half8 v; unsigned int u[4]; } kaU, kbU;
        kaU.v = ra;
        kbU.v = rb;
#pragma unroll
        for (int c = 0; c < 4; ++c) {
            const unsigned int ua = kaU.u[c];
            const unsigned int ub = kbU.u[c];
            const unsigned int lo = __builtin_amdgcn_perm(ub, ua, 0x05040100);
            const unsigned int hi = __builtin_amdgcn_perm(ub, ua, 0x07060302);
            const int d0 = (cc << 3) + (c << 1);
            const int pos = ((jch ^ cc) << 3) + jo;
            *(unsigned int*)(&KT[d0 * PITCH + pos]) = lo;
            *(unsigned int*)(&KT[(d0 + 1) * PITCH + pos]) = hi;
        }
        // ---- prefetch tile kt+1 (wraps within split; stays in flight across barrier) ----
        const int ktn = kt0 + ((it + 1) & (nkt - 1));
        const unsigned short* kgn = Hb + (((ktn << 6) + (p << 1)) << 6) + (cc << 3);
        ra = *(const half8*)(kgn);
        rb = *(const half8*)(kgn + 64);

        barrier_lds_only();

        // ---- S^T = K * Q^T : A = K rows from LDS, shared across groups ----
        floatx4 a[QG][4];
#pragma unroll
        for (int jt = 0; jt < 4; ++jt) {
            const half8 k0 = *(const half8*)(&KS[((jt << 4) + m) * PITCH + (quad << 3)]);
            const half8 k1 = *(const half8*)(&KS[((jt << 4) + m) * PITCH + 32 + (quad << 3)]);
#pragma unroll
            for (int g = 0; g < QG; ++g) {
                floatx4 z = {0.f, 0.f, 0.f, 0.f};
                z = __builtin_amdgcn_mfma_f32_16x16x32_f16(k0, bq0[g], z, 0, 0, 0);
                z = __builtin_amdgcn_mfma_f32_16x16x32_f16(k1, bq1[g], z, 0, 0, 0);
                a[g][jt] = z;
            }
        }

        // ---- per group: mask, online softmax, Ps write, O rescale ----
#pragma unroll
        for (int g = 0; g < QG; ++g) {
            const int mrow = gq[g] << 6;
            const unsigned int w0 = mbits[mrow + (kt << 1)];
            const unsigned int w1 = mbits[mrow + (kt << 1) + 1];

            float tmx = MRINIT;
#pragma unroll
            for (int jt = 0; jt < 4; ++jt) {
                const unsigned int wv = (jt < 2) ? w0 : w1;
                const unsigned int bits = (wv >> (((jt & 1) << 4) + (quad << 2))) & 0xFu;
#pragma unroll
                for (int reg = 0; reg < 4; ++reg) {
                    const float v = ((bits >> reg) & 1u) ? a[g][jt][reg] : MRINIT;
                    a[g][jt][reg] = v;
                    tmx = fmaxf(tmx, v);
                }
            }
            tmx = fmaxf(tmx, __shfl_xor(tmx, 16));
            tmx = fmaxf(tmx, __shfl_xor(tmx, 32));
            const float mnew = fmaxf(mr[g], tmx);
            const float alpha = __builtin_amdgcn_exp2f(mr[g] - mnew);
            const bool need = __any(mnew > mr[g]);

            float psum = 0.f;
#pragma unroll
            for (int jt = 0; jt < 4; ++jt) {
                const float p0 = __builtin_amdgcn_exp2f(a[g][jt][0] - mnew);
                const float p1 = __builtin_amdgcn_exp2f(a[g][jt][1] - mnew);
                const float p2 = __builtin_amdgcn_exp2f(a[g][jt][2] - mnew);
                const float p3 = __builtin_amdgcn_exp2f(a[g][jt][3] - mnew);
                psum += (p0 + p1) + (p2 + p3);
                const int ch = (jt << 1) + (quad >> 1);
                *(uint2*)(&Ps[psb[g] + ((ch ^ msw) << 3) + ((quad & 1) << 2)]) =
                    make_uint2(pk2h(p0, p1), pk2h(p2, p3));
            }
            psum += __shfl_xor(psum, 16);
            psum += __shfl_xor(psum, 32);
            lr[g] = lr[g] * alpha + psum;
            mr[g] = mnew;

            if (need) {
                const float aO0 = __shfl(alpha, (quad << 2) + 0);
                const float aO1 = __shfl(alpha, (quad << 2) + 1);
                const float aO2 = __shfl(alpha, (quad << 2) + 2);
                const float aO3 = __shfl(alpha, (quad << 2) + 3);
#pragma unroll
                for (int nt = 0; nt < 4; ++nt) {
                    O[g][nt][0] *= aO0;
                    O[g][nt][1] *= aO1;
                    O[g][nt][2] *= aO2;
                    O[g][nt][3] *= aO3;
                }
            }
        }

        __builtin_amdgcn_wave_barrier();
        __asm__ __volatile__("" ::: "memory");

        // ---- O += P * V ----
        half8 pa0[QG], pa1[QG];
#pragma unroll
        for (int g = 0; g < QG; ++g) {
            pa0[g] = *(const half8*)(&Ps[psb[g] + ((quad ^ msw) << 3)]);
            pa1[g] = *(const half8*)(&Ps[psb[g] + (((4 + quad) ^ msw) << 3)]);
        }
#pragma unroll
        for (int nt = 0; nt < 4; ++nt) {
            const int d = (nt << 4) + m;
            const int sw = (d >> 3) & 7;
            const half8 v0 = *(const half8*)(&KT[d * PITCH + ((quad ^ sw) << 3)]);
            const half8 v1 = *(const half8*)(&KT[d * PITCH + (((4 + quad) ^ sw) << 3)]);
#pragma unroll
            for (int g = 0; g < QG; ++g) {
                O[g][nt] = __builtin_amdgcn_mfma_f32_16x16x32_f16(pa0[g], v0, O[g][nt], 0, 0, 0);
                O[g][nt] = __builtin_amdgcn_mfma_f32_16x16x32_f16(pa1[g], v1, O[g][nt], 0, 0, 0);
            }
        }
    }

    // ---- epilogue ----
    if (OUTMODE == 2) {
        // split-K partials: un-normalized O (fp32) + per-row (m, l); bias/leaky/LN in combine
        float* Ob = (float*)OutP +
                    ((((size_t)(split << 3) + mat) * NN + wbase + (quad << 2)) << 6) + m;
#pragma unroll
        for (int reg = 0; reg < 4; ++reg)
#pragma unroll
            for (int nt = 0; nt < 4; ++nt)
                Ob[(reg << 6) + (nt << 4)] = O[0][nt][reg];
        if (lane < 16)
            mlP[((size_t)(split << 3) + mat) * NN + wbase + m] = make_float2(mr[0], lr[0]);
        return;
    }

    float g0, g1, g2, g3, be0, be1, be2, be3;
    if (OUTMODE == 1) {
        g0 = gamma[m]; g1 = gamma[16 + m]; g2 = gamma[32 + m]; g3 = gamma[48 + m];
        be0 = beta[m]; be1 = beta[16 + m]; be2 = beta[32 + m]; be3 = beta[48 + m];
    }
#pragma unroll
    for (int g = 0; g < QG; ++g) {
        const float l0 = 1.f / __shfl(lr[g], (quad << 2) + 0);
        const float l1 = 1.f / __shfl(lr[g], (quad << 2) + 1);
        const float l2 = 1.f / __shfl(lr[g], (quad << 2) + 2);
        const float l3 = 1.f / __shfl(lr[g], (quad << 2) + 3);
        const size_t obase = (((size_t)mat * NN + wbase + (g << 4) + (quad << 2)) << 6) + m;
#pragma unroll
        for (int reg = 0; reg < 4; ++reg) {
            const float li = (reg == 0) ? l0 : (reg == 1) ? l1 : (reg == 2) ? l2 : l3;
            float z0 = O[g][0][reg] * li + bv0;
            float z1 = O[g][1][reg] * li + bv1;
            float z2 = O[g][2][reg] * li + bv2;
            float z3 = O[g][3][reg] * li + bv3;
            z0 = (z0 > 0.f) ? z0 : 0.2f * z0;
            z1 = (z1 > 0.f) ? z1 : 0.2f * z1;
            z2 = (z2 > 0.f) ? z2 : 0.2f * z2;
            z3 = (z3 > 0.f) ? z3 : 0.2f * z3;
            if (OUTMODE == 0) {
                unsigned short* op = (unsigned short*)OutP + obase + ((size_t)reg << 6);
                op[0] = f2h(z0); op[16] = f2h(z1); op[32] = f2h(z2); op[48] = f2h(z3);
            } else {
                float s = ((z0 + z1) + (z2 + z3));
                float sq = ((z0 * z0 + z1 * z1) + (z2 * z2 + z3 * z3));
#pragma unroll
                for (int off = 1; off < 16; off <<= 1) {
                    s += __shfl_xor(s, off);
                    sq += __shfl_xor(sq, off);
                }
                const float mu = s * 0.015625f;
                float var = sq * 0.015625f - mu * mu;
                var = fmaxf(var, 0.f);
                const float rstd = rsqrtf(var + 1e-5f);
                float* op = (float*)OutP + obase + ((size_t)reg << 6);
                op[0]  = (z0 - mu) * rstd * g0 + be0;
                op[16] = (z1 - mu) * rstd * g1 + be1;
                op[32] = (z2 - mu) * rstd * g2 + be2;
                op[48] = (z3 - mu) * rstd * g3 + be3;
            }
        }
    }
}

// ---------- mix as MFMA GEMM: h2[b,r,d] = sum_k z[b,r,k] * Wo[d,k]  (z leaky-pre-applied) ----------
// 256 blocks (8 b x 32 row-tiles of 64); A = z rows, B[k][n=d] = Wo[d][k] (row-major b128 reads).
__global__ __launch_bounds__(256) void mix_gemm(const unsigned short* __restrict__ oh,
                                                const float* __restrict__ Wo,
                                                unsigned short* __restrict__ h2) {
    __shared__ unsigned short zs[64 * MPITCH];   // z [row][k] fp16, k head-major
    __shared__ unsigned short wsm[64 * MPITCH];  // Wo [d][k] fp16
    const int t = threadIdx.x;
    const int b = blockIdx.x >> 5;
    const int n0 = (blockIdx.x & 31) << 6;
    // stage z: 64 rows x 256 k (k = hh*64 + d); oh is [b*4+hh][row][64] fp16
    for (int i = t; i < 2048; i += 256) {
        const int hh = i >> 9;
        const int r = (i >> 3) & 63;
        const int d8 = i & 7;
        const half8 v = *(const half8*)(oh + ((((size_t)b << 2) + hh) * NN + n0 + r) * 64 + (d8 << 3));
        *(half8*)(&zs[r * MPITCH + (hh << 6) + (d8 << 3)]) = v;
    }
    // stage Wo (fp32 -> fp16): 64 d x 256 k
    for (int i = t; i < 2048; i += 256) {
        const int d = i >> 5;
        const int k0 = (i & 31) << 3;
        const float4 f0 = *(const float4*)(Wo + (d << 8) + k0);
        const float4 f1 = *(const float4*)(Wo + (d << 8) + k0 + 4);
        uint4 pk;
        pk.x = pk2h(f0.x, f0.y);
        pk.y = pk2h(f0.z, f0.w);
        pk.z = pk2h(f1.x, f1.y);
        pk.w = pk2h(f1.z, f1.w);
        *(uint4*)(&wsm[d * MPITCH + k0]) = pk;
    }
    __syncthreads();
    const int wave = t >> 6;
    const int m = t & 15;
    const int quad = (t >> 4) & 3;
    const int ar = (wave << 4) + m;
    floatx4 acc[4] = {{0.f, 0.f, 0.f, 0.f}, {0.f, 0.f, 0.f, 0.f},
                      {0.f, 0.f, 0.f, 0.f}, {0.f, 0.f, 0.f, 0.f}};
#pragma unroll
    for (int chunk = 0; chunk < 8; ++chunk) {
        const int k0 = chunk << 5;
        const half8 af = *(const half8*)(&zs[ar * MPITCH + k0 + (quad << 3)]);
#pragma unroll
        for (int nt = 0; nt < 4; ++nt) {
            const half8 bf = *(const half8*)(&wsm[((nt << 4) + m) * MPITCH + k0 + (quad << 3)]);
            acc[nt] = __builtin_amdgcn_mfma_f32_16x16x32_f16(af, bf, acc[nt], 0, 0, 0);
        }
    }
    // D[row=4quad+reg within wave-tile][d=16nt+m]
    unsigned short* hp = h2 + (((size_t)b * NN + n0 + (wave << 4) + (quad << 2)) << 6) + m;
#pragma unroll
    for (int reg = 0; reg < 4; ++reg)
#pragma unroll
        for (int nt = 0; nt < 4; ++nt)
            hp[(reg << 6) + (nt << 4)] = f2h(acc[nt][reg]);
}

// ---------- combine split-K partials + bias + leaky + LayerNorm (fp32 out) ----------
__global__ __launch_bounds__(256) void combine_ln(const float* __restrict__ Opart,
                                                  const float2* __restrict__ ml,
                                                  const float* __restrict__ bo,
                                                  const float* __restrict__ gamma,
                                                  const float* __restrict__ beta,
                                                  float* __restrict__ out) {
    const int t = threadIdx.x;
    const int lane = t & 63;
    const int widx = (blockIdx.x << 2) + (t >> 6);  // 0..16383 = mat*2048 + row
    const size_t r0 = (size_t)widx;
    const float2 s0 = ml[r0];
    const float2 s1 = ml[(size_t)(NN * 8) + r0];
    const float mm = fmaxf(s0.x, s1.x);
    const float c0 = __builtin_amdgcn_exp2f(s0.x - mm);
    const float c1 = __builtin_amdgcn_exp2f(s1.x - mm);
    const float l = s0.y * c0 + s1.y * c1;
    const float o0 = Opart[(r0 << 6) + lane];
    const float o1 = Opart[(((size_t)(NN * 8) + r0) << 6) + lane];
    float v = (o0 * c0 + o1 * c1) / l + bo[lane];
    v = (v > 0.f) ? v : 0.2f * v;
    float s = v;
    float sq = v * v;
#pragma unroll
    for (int off = 1; off < 64; off <<= 1) {
        s += __shfl_xor(s, off);
        sq += __shfl_xor(sq, off);
    }
    const float mu = s * 0.015625f;
    float var = sq * 0.015625f - mu * mu;
    var = fmaxf(var, 0.f);
    const float rstd = rsqrtf(var + 1e-5f);
    out[(r0 << 6) + lane] = (v - mu) * rstd * gamma[lane] + beta[lane];
}

extern "C" void kernel_launch(void* const* d_in, const int* in_sizes, int n_in,
                              void* d_out, int out_size, void* d_ws, size_t ws_size,
                              hipStream_t stream) {
    const float* x     = (const float*)d_in[0];
    const int*   graph = (const int*)d_in[1];
    const float* Wh    = (const float*)d_in[2];
    const float* bh    = (const float*)d_in[3];
    const float* Wo    = (const float*)d_in[4];
    const float* bo    = (const float*)d_in[5];
    const float* gamma = (const float*)d_in[6];
    const float* beta  = (const float*)d_in[7];
    float* out = (float*)d_out;

    // ---- workspace layout (16.75 MB, with reuse) ----
    // [0, 0.5M):      mbits
    // [0.5M, 8.5M):   h fp16 (dead after gat1) -> h2 overlays [0.5M, 2.5M); ml at [2.5M, 2.75M)
    // [8.5M, 16.5M):  oh fp16 (dead after mix) -> Opart fp32 overlays (8MB: 2 splits x 8 x 2048 x 64)
    char* ws = (char*)d_ws;
    unsigned int* mbits = (unsigned int*)ws;
    unsigned short* h   = (unsigned short*)(ws + 0x080000);
    unsigned short* oh  = (unsigned short*)(ws + 0x880000);
    unsigned short* h2  = (unsigned short*)(ws + 0x080000);  // overlays h
    float2* ml          = (float2*)(ws + 0x280000);          // 256KB, in dead h region
    float* Opart        = (float*)(ws + 0x880000);           // overlays oh

    mask_kernel<<<16384, 256, 0, stream>>>(graph, mbits);
    proj_kernel<<<4096, 256, 0, stream>>>(x, Wh, h);
    gat_flash<2, 0><<<512, 256, 0, stream>>>(h, mbits, bh, 4, nullptr, nullptr, oh, nullptr);
    mix_gemm<<<256, 256, 0, stream>>>(oh, Wo, h2);
    gat_flash<1, 2><<<512, 256, 0, stream>>>(h2, mbits, bo, 1, nullptr, nullptr, Opart, ml);
    combine_ln<<<4096, 256, 0, stream>>>(Opart, ml, bo, gamma, beta, out);
}

// Round 12
// 219.750 us; speedup vs baseline: 1.2492x; 1.0706x over previous
//
#include <hip/hip_runtime.h>

#define NN 2048
#define PITCH 72   // u16 elems per LDS row (gat): 144B -> 16B-aligned rows
#define MPITCH 264 // u16 elems per LDS row (mix): 528B, bank-shift 4/row

typedef __attribute__((ext_vector_type(8))) _Float16 half8;  // 8 fp16 = 4 VGPRs (MFMA A/B frag)
typedef __attribute__((ext_vector_type(4))) float floatx4;   // MFMA C/D frag

static_assert(sizeof(half8) == 16, "");

#define MRINIT -3.0e38f

__device__ __forceinline__ unsigned short f2h(float f) {
    union { _Float16 h; unsigned short u; } v;
    v.h = (_Float16)f;  // RNE
    return v.u;
}
__device__ __forceinline__ float h2f(unsigned short u) {
    union { unsigned short u; _Float16 h; } v;
    v.u = u;
    return (float)v.h;
}
__device__ __forceinline__ unsigned int pk2h(float a, float b) {  // v_cvt_pkrtz_f16_f32
    union { __fp16 __attribute__((ext_vector_type(2))) h; unsigned int u; } v;
    v.h = __builtin_amdgcn_cvt_pkrtz(a, b);
    return v.u;
}
// barrier that does NOT drain vmcnt: LDS-visibility only; prefetch loads stay in flight.
__device__ __forceinline__ void barrier_lds_only() {
    __asm__ __volatile__("" ::: "memory");
    __builtin_amdgcn_s_waitcnt(0xC07F);  // vmcnt=63, expcnt=7, lgkmcnt=0
    __builtin_amdgcn_s_barrier();
    __asm__ __volatile__("" ::: "memory");
}

// ---------- mask = (graph + I) > 0, packed to bits ----------
__global__ __launch_bounds__(256) void mask_kernel(const int* __restrict__ graph,
                                                   unsigned int* __restrict__ mbits) {
    const int t = threadIdx.x;
    const int lane = t & 63;
    const int W = (blockIdx.x << 2) + (t >> 6);
    const int i = W >> 5;
    const int cb = W & 31;
    const int j = (cb << 6) + lane;
    const int g = graph[(size_t)i * NN + j];
    const unsigned long long bal = __ballot((g > 0) || (i == j));
    if (lane == 0)  mbits[(i << 6) + (cb << 1)]     = (unsigned int)bal;
    if (lane == 32) mbits[(i << 6) + (cb << 1) + 1] = (unsigned int)(bal >> 32);
}

// ---------- h[b,h,n,d] = sum_c x[b,n,c] * Wh[h,d,c]  (fp32 in, fp16 out) ----------
__global__ __launch_bounds__(256) void proj_kernel(const float* __restrict__ x,
                                                   const float* __restrict__ Wh,
                                                   unsigned short* __restrict__ hout) {
    __shared__ float xs[16 * 64];
    __shared__ float wsh[64 * 65];
    const int t = threadIdx.x;
    const int pair = blockIdx.x >> 7;
    const int nt = blockIdx.x & 127;
    const int n0 = nt << 4;
    const int b = pair >> 2;
    const int hh = pair & 3;
    const float* xb = x + (((size_t)b * NN + n0) << 6);
    for (int i = t; i < 1024; i += 256) xs[i] = xb[i];
    const float* wb = Wh + (hh << 12);
    for (int i = t; i < 4096; i += 256) wsh[(i >> 6) * 65 + (i & 63)] = wb[i];
    __syncthreads();
    const int d = t & 63;
    const int q = t >> 6;
    float a0 = 0.f, a1 = 0.f, a2 = 0.f, a3 = 0.f;
    for (int c = 0; c < 64; ++c) {
        const float w = wsh[d * 65 + c];
        a0 += xs[(((q << 2) + 0) << 6) + c] * w;
        a1 += xs[(((q << 2) + 1) << 6) + c] * w;
        a2 += xs[(((q << 2) + 2) << 6) + c] * w;
        a3 += xs[(((q << 2) + 3) << 6) + c] * w;
    }
    unsigned short* ho = hout + (((size_t)pair * NN + n0 + (q << 2)) << 6) + d;
    ho[0]   = f2h(a0);
    ho[64]  = f2h(a1);
    ho[128] = f2h(a2);
    ho[192] = f2h(a3);
}

// ---------- fused GAT layer (r9 core, rotation swizzles) ----------
// OUTMODE 0: fp16 out, leaky fused. OUTMODE 1: fused leaky+LN fp32. OUTMODE 2: split-K
// partials (un-normalized O fp32 + per-row (m,l)); grid carries a split bit; 16 K-tiles.
// Swizzle: physical chunk = (logical + row) & 7 (rotation). Bank group = (2s+const)&7
// -> uniform across lanes for Ps writes / pa reads / Kts writes / V reads (XOR collapsed).
template <int QG, int OUTMODE>
__global__ __launch_bounds__(256) void gat_flash(const unsigned short* __restrict__ Hm,
                                                 const unsigned int* __restrict__ mbits,
                                                 const float* __restrict__ bias,
                                                 const int bias_mod,
                                                 const float* __restrict__ gamma,
                                                 const float* __restrict__ beta,
                                                 void* __restrict__ OutP,
                                                 float2* __restrict__ mlP) {
    __shared__ unsigned short Ks[2][64 * PITCH];
    __shared__ unsigned short Kts[2][64 * PITCH];
    __shared__ unsigned short Ps[4 * QG * 16 * PITCH];

    const int t = threadIdx.x;
    const int wave = t >> 6;
    const int lane = t & 63;
    const int quad = lane >> 4;
    const int m = lane & 15;

    const int qtbits = (QG == 2) ? 4 : 5;
    const int bid = blockIdx.x;
    const int qt = bid & ((1 << qtbits) - 1);
    const int split = (OUTMODE == 2) ? ((bid >> qtbits) & 1) : 0;
    const int mat = bid >> (qtbits + ((OUTMODE == 2) ? 1 : 0));
    const int q0 = qt << ((QG == 2) ? 7 : 6);
    const int nkt = (OUTMODE == 2) ? 16 : 32;
    const int kt0 = split * nkt;

    const unsigned short* Hb = Hm + ((size_t)mat << 17);
    const int wbase = q0 + wave * (16 * QG);

    const _Float16 LOG2E = (_Float16)1.44269504f;
    half8 bq0[QG], bq1[QG];
    int gq[QG];
#pragma unroll
    for (int g = 0; g < QG; ++g) {
        gq[g] = wbase + (g << 4) + m;
        bq0[g] = *(const half8*)(Hb + (gq[g] << 6) + (quad << 3)) * LOG2E;
        bq1[g] = *(const half8*)(Hb + (gq[g] << 6) + 32 + (quad << 3)) * LOG2E;
    }

    const int boff = (mat % bias_mod) << 6;
    const float bv0 = bias[boff + m];
    const float bv1 = bias[boff + 16 + m];
    const float bv2 = bias[boff + 32 + m];
    const float bv3 = bias[boff + 48 + m];

    const int p = t >> 3;
    const int cc = t & 7;
    const int jch = p >> 2;
    const int jo = (p & 3) << 1;

    float mr[QG], lr[QG];
    floatx4 O[QG][4];
#pragma unroll
    for (int g = 0; g < QG; ++g) {
        mr[g] = MRINIT;
        lr[g] = 0.f;
#pragma unroll
        for (int nt = 0; nt < 4; ++nt) O[g][nt] = floatx4{0.f, 0.f, 0.f, 0.f};
    }

    const int msw = m & 7;
    int psb[QG];
#pragma unroll
    for (int g = 0; g < QG; ++g) psb[g] = (wave * QG + g) * 1152 + m * PITCH;

    // ---- prefetch tile kt0 into registers ----
    const unsigned short* kg0 = Hb + (((kt0 << 6) + (p << 1)) << 6) + (cc << 3);
    half8 ra = *(const half8*)(kg0);
    half8 rb = *(const half8*)(kg0 + 64);

    for (int it = 0; it < nkt; ++it) {
        const int kt = kt0 + it;
        unsigned short* KS = Ks[it & 1];
        unsigned short* KT = Kts[it & 1];
        // ---- write prefetched tile kt (VGPR->LDS); vmcnt wait lands here, one iter late ----
        *(half8*)(&KS[(p << 1) * PITCH + (cc << 3)]) = ra;
        *(half8*)(&KS[((p << 1) + 1) * PITCH + (cc << 3)]) = rb;
        union { half8 v; unsigned int u[4]; } kaU, kbU;
        kaU.v = ra;
        kbU.v = rb;
#pragma unroll
        for (int c = 0; c < 4; ++c) {
            const unsigned int ua = kaU.u[c];
            const unsigned int ub = kbU.u[c];
            const unsigned int lo = __builtin_amdgcn_perm(ub, ua, 0x05040100);
            const unsigned int hi = __builtin_amdgcn_perm(ub, ua, 0x07060302);
            const int d0 = (cc << 3) + (c << 1);
            const int pos = (((jch + cc) & 7) << 3) + jo;  // rotation swizzle
            *(unsigned int*)(&KT[d0 * PITCH + pos]) = lo;
            *(unsigned int*)(&KT[(d0 + 1) * PITCH + pos]) = hi;
        }
        // ---- prefetch tile kt+1 (wraps within split; stays in flight across barrier) ----
        const int ktn = kt0 + ((it + 1) & (nkt - 1));
        const unsigned short* kgn = Hb + (((ktn << 6) + (p << 1)) << 6) + (cc << 3);
        ra = *(const half8*)(kgn);
        rb = *(const half8*)(kgn + 64);

        barrier_lds_only();

        // ---- S^T = K * Q^T : A = K rows from LDS, shared across groups ----
        floatx4 a[QG][4];
#pragma unroll
        for (int jt = 0; jt < 4; ++jt) {
            const half8 k0 = *(const half8*)(&KS[((jt << 4) + m) * PITCH + (quad << 3)]);
            const half8 k1 = *(const half8*)(&KS[((jt << 4) + m) * PITCH + 32 + (quad << 3)]);
#pragma unroll
            for (int g = 0; g < QG; ++g) {
                floatx4 z = {0.f, 0.f, 0.f, 0.f};
                z = __builtin_amdgcn_mfma_f32_16x16x32_f16(k0, bq0[g], z, 0, 0, 0);
                z = __builtin_amdgcn_mfma_f32_16x16x32_f16(k1, bq1[g], z, 0, 0, 0);
                a[g][jt] = z;
            }
        }

        // ---- per group: mask, online softmax, Ps write, O rescale ----
#pragma unroll
        for (int g = 0; g < QG; ++g) {
            const int mrow = gq[g] << 6;
            const unsigned int w0 = mbits[mrow + (kt << 1)];
            const unsigned int w1 = mbits[mrow + (kt << 1) + 1];

            float tmx = MRINIT;
#pragma unroll
            for (int jt = 0; jt < 4; ++jt) {
                const unsigned int wv = (jt < 2) ? w0 : w1;
                const unsigned int bits = (wv >> (((jt & 1) << 4) + (quad << 2))) & 0xFu;
#pragma unroll
                for (int reg = 0; reg < 4; ++reg) {
                    const float v = ((bits >> reg) & 1u) ? a[g][jt][reg] : MRINIT;
                    a[g][jt][reg] = v;
                    tmx = fmaxf(tmx, v);
                }
            }
            tmx = fmaxf(tmx, __shfl_xor(tmx, 16));
            tmx = fmaxf(tmx, __shfl_xor(tmx, 32));
            const float mnew = fmaxf(mr[g], tmx);
            const float alpha = __builtin_amdgcn_exp2f(mr[g] - mnew);
            const bool need = __any(mnew > mr[g]);

            float psum = 0.f;
#pragma unroll
            for (int jt = 0; jt < 4; ++jt) {
                const float p0 = __builtin_amdgcn_exp2f(a[g][jt][0] - mnew);
                const float p1 = __builtin_amdgcn_exp2f(a[g][jt][1] - mnew);
                const float p2 = __builtin_amdgcn_exp2f(a[g][jt][2] - mnew);
                const float p3 = __builtin_amdgcn_exp2f(a[g][jt][3] - mnew);
                psum += (p0 + p1) + (p2 + p3);
                const int ch = (jt << 1) + (quad >> 1);
                *(uint2*)(&Ps[psb[g] + (((ch + msw) & 7) << 3) + ((quad & 1) << 2)]) =
                    make_uint2(pk2h(p0, p1), pk2h(p2, p3));  // rotation swizzle
            }
            psum += __shfl_xor(psum, 16);
            psum += __shfl_xor(psum, 32);
            lr[g] = lr[g] * alpha + psum;
            mr[g] = mnew;

            if (need) {
                const float aO0 = __shfl(alpha, (quad << 2) + 0);
                const float aO1 = __shfl(alpha, (quad << 2) + 1);
                const float aO2 = __shfl(alpha, (quad << 2) + 2);
                const float aO3 = __shfl(alpha, (quad << 2) + 3);
#pragma unroll
                for (int nt = 0; nt < 4; ++nt) {
                    O[g][nt][0] *= aO0;
                    O[g][nt][1] *= aO1;
                    O[g][nt][2] *= aO2;
                    O[g][nt][3] *= aO3;
                }
            }
        }

        __builtin_amdgcn_wave_barrier();
        __asm__ __volatile__("" ::: "memory");

        // ---- O += P * V ----
        half8 pa0[QG], pa1[QG];
#pragma unroll
        for (int g = 0; g < QG; ++g) {
            pa0[g] = *(const half8*)(&Ps[psb[g] + (((quad + msw) & 7) << 3)]);
            pa1[g] = *(const half8*)(&Ps[psb[g] + (((4 + quad + msw) & 7) << 3)]);
        }
#pragma unroll
        for (int nt = 0; nt < 4; ++nt) {
            const int d = (nt << 4) + m;
            const int sw = (d >> 3) & 7;
            const half8 v0 = *(const half8*)(&KT[d * PITCH + (((quad + sw) & 7) << 3)]);
            const half8 v1 = *(const half8*)(&KT[d * PITCH + (((4 + quad + sw) & 7) << 3)]);
#pragma unroll
            for (int g = 0; g < QG; ++g) {
                O[g][nt] = __builtin_amdgcn_mfma_f32_16x16x32_f16(pa0[g], v0, O[g][nt], 0, 0, 0);
                O[g][nt] = __builtin_amdgcn_mfma_f32_16x16x32_f16(pa1[g], v1, O[g][nt], 0, 0, 0);
            }
        }
    }

    // ---- epilogue ----
    if (OUTMODE == 2) {
        float* Ob = (float*)OutP +
                    ((((size_t)(split << 3) + mat) * NN + wbase + (quad << 2)) << 6) + m;
#pragma unroll
        for (int reg = 0; reg < 4; ++reg)
#pragma unroll
            for (int nt = 0; nt < 4; ++nt)
                Ob[(reg << 6) + (nt << 4)] = O[0][nt][reg];
        if (lane < 16)
            mlP[((size_t)(split << 3) + mat) * NN + wbase + m] = make_float2(mr[0], lr[0]);
        return;
    }

    float g0, g1, g2, g3, be0, be1, be2, be3;
    if (OUTMODE == 1) {
        g0 = gamma[m]; g1 = gamma[16 + m]; g2 = gamma[32 + m]; g3 = gamma[48 + m];
        be0 = beta[m]; be1 = beta[16 + m]; be2 = beta[32 + m]; be3 = beta[48 + m];
    }
#pragma unroll
    for (int g = 0; g < QG; ++g) {
        const float l0 = 1.f / __shfl(lr[g], (quad << 2) + 0);
        const float l1 = 1.f / __shfl(lr[g], (quad << 2) + 1);
        const float l2 = 1.f / __shfl(lr[g], (quad << 2) + 2);
        const float l3 = 1.f / __shfl(lr[g], (quad << 2) + 3);
        const size_t obase = (((size_t)mat * NN + wbase + (g << 4) + (quad << 2)) << 6) + m;
#pragma unroll
        for (int reg = 0; reg < 4; ++reg) {
            const float li = (reg == 0) ? l0 : (reg == 1) ? l1 : (reg == 2) ? l2 : l3;
            float z0 = O[g][0][reg] * li + bv0;
            float z1 = O[g][1][reg] * li + bv1;
            float z2 = O[g][2][reg] * li + bv2;
            float z3 = O[g][3][reg] * li + bv3;
            z0 = (z0 > 0.f) ? z0 : 0.2f * z0;
            z1 = (z1 > 0.f) ? z1 : 0.2f * z1;
            z2 = (z2 > 0.f) ? z2 : 0.2f * z2;
            z3 = (z3 > 0.f) ? z3 : 0.2f * z3;
            if (OUTMODE == 0) {
                unsigned short* op = (unsigned short*)OutP + obase + ((size_t)reg << 6);
                op[0] = f2h(z0); op[16] = f2h(z1); op[32] = f2h(z2); op[48] = f2h(z3);
            } else {
                float s = ((z0 + z1) + (z2 + z3));
                float sq = ((z0 * z0 + z1 * z1) + (z2 * z2 + z3 * z3));
#pragma unroll
                for (int off = 1; off < 16; off <<= 1) {
                    s += __shfl_xor(s, off);
                    sq += __shfl_xor(sq, off);
                }
                const float mu = s * 0.015625f;
                float var = sq * 0.015625f - mu * mu;
                var = fmaxf(var, 0.f);
                const float rstd = rsqrtf(var + 1e-5f);
                float* op = (float*)OutP + obase + ((size_t)reg << 6);
                op[0]  = (z0 - mu) * rstd * g0 + be0;
                op[16] = (z1 - mu) * rstd * g1 + be1;
                op[32] = (z2 - mu) * rstd * g2 + be2;
                op[48] = (z3 - mu) * rstd * g3 + be3;
            }
        }
    }
}

// ---------- mix as MFMA GEMM: h2[b,r,d] = sum_k z[b,r,k] * Wo[d,k]  (z leaky-pre-applied) ----------
__global__ __launch_bounds__(256) void mix_gemm(const unsigned short* __restrict__ oh,
                                                const float* __restrict__ Wo,
                                                unsigned short* __restrict__ h2) {
    __shared__ unsigned short zs[64 * MPITCH];   // z [row][k] fp16, k head-major
    __shared__ unsigned short wsm[64 * MPITCH];  // Wo [d][k] fp16
    const int t = threadIdx.x;
    const int b = blockIdx.x >> 5;
    const int n0 = (blockIdx.x & 31) << 6;
    for (int i = t; i < 2048; i += 256) {
        const int hh = i >> 9;
        const int r = (i >> 3) & 63;
        const int d8 = i & 7;
        const half8 v = *(const half8*)(oh + ((((size_t)b << 2) + hh) * NN + n0 + r) * 64 + (d8 << 3));
        *(half8*)(&zs[r * MPITCH + (hh << 6) + (d8 << 3)]) = v;
    }
    for (int i = t; i < 2048; i += 256) {
        const int d = i >> 5;
        const int k0 = (i & 31) << 3;
        const float4 f0 = *(const float4*)(Wo + (d << 8) + k0);
        const float4 f1 = *(const float4*)(Wo + (d << 8) + k0 + 4);
        uint4 pk;
        pk.x = pk2h(f0.x, f0.y);
        pk.y = pk2h(f0.z, f0.w);
        pk.z = pk2h(f1.x, f1.y);
        pk.w = pk2h(f1.z, f1.w);
        *(uint4*)(&wsm[d * MPITCH + k0]) = pk;
    }
    __syncthreads();
    const int wave = t >> 6;
    const int m = t & 15;
    const int quad = (t >> 4) & 3;
    const int ar = (wave << 4) + m;
    floatx4 acc[4] = {{0.f, 0.f, 0.f, 0.f}, {0.f, 0.f, 0.f, 0.f},
                      {0.f, 0.f, 0.f, 0.f}, {0.f, 0.f, 0.f, 0.f}};
#pragma unroll
    for (int chunk = 0; chunk < 8; ++chunk) {
        const int k0 = chunk << 5;
        const half8 af = *(const half8*)(&zs[ar * MPITCH + k0 + (quad << 3)]);
#pragma unroll
        for (int nt = 0; nt < 4; ++nt) {
            const half8 bf = *(const half8*)(&wsm[((nt << 4) + m) * MPITCH + k0 + (quad << 3)]);
            acc[nt] = __builtin_amdgcn_mfma_f32_16x16x32_f16(af, bf, acc[nt], 0, 0, 0);
        }
    }
    unsigned short* hp = h2 + (((size_t)b * NN + n0 + (wave << 4) + (quad << 2)) << 6) + m;
#pragma unroll
    for (int reg = 0; reg < 4; ++reg)
#pragma unroll
        for (int nt = 0; nt < 4; ++nt)
            hp[(reg << 6) + (nt << 4)] = f2h(acc[nt][reg]);
}

// ---------- combine split-K partials + bias + leaky + LayerNorm (fp32 out) ----------
__global__ __launch_bounds__(256) void combine_ln(const float* __restrict__ Opart,
                                                  const float2* __restrict__ ml,
                                                  const float* __restrict__ bo,
                                                  const float* __restrict__ gamma,
                                                  const float* __restrict__ beta,
                                                  float* __restrict__ out) {
    const int t = threadIdx.x;
    const int lane = t & 63;
    const int widx = (blockIdx.x << 2) + (t >> 6);
    const size_t r0 = (size_t)widx;
    const float2 s0 = ml[r0];
    const float2 s1 = ml[(size_t)(NN * 8) + r0];
    const float mm = fmaxf(s0.x, s1.x);
    const float c0 = __builtin_amdgcn_exp2f(s0.x - mm);
    const float c1 = __builtin_amdgcn_exp2f(s1.x - mm);
    const float l = s0.y * c0 + s1.y * c1;
    const float o0 = Opart[(r0 << 6) + lane];
    const float o1 = Opart[(((size_t)(NN * 8) + r0) << 6) + lane];
    float v = (o0 * c0 + o1 * c1) / l + bo[lane];
    v = (v > 0.f) ? v : 0.2f * v;
    float s = v;
    float sq = v * v;
#pragma unroll
    for (int off = 1; off < 64; off <<= 1) {
        s += __shfl_xor(s, off);
        sq += __shfl_xor(sq, off);
    }
    const float mu = s * 0.015625f;
    float var = sq * 0.015625f - mu * mu;
    var = fmaxf(var, 0.f);
    const float rstd = rsqrtf(var + 1e-5f);
    out[(r0 << 6) + lane] = (v - mu) * rstd * gamma[lane] + beta[lane];
}

extern "C" void kernel_launch(void* const* d_in, const int* in_sizes, int n_in,
                              void* d_out, int out_size, void* d_ws, size_t ws_size,
                              hipStream_t stream) {
    const float* x     = (const float*)d_in[0];
    const int*   graph = (const int*)d_in[1];
    const float* Wh    = (const float*)d_in[2];
    const float* bh    = (const float*)d_in[3];
    const float* Wo    = (const float*)d_in[4];
    const float* bo    = (const float*)d_in[5];
    const float* gamma = (const float*)d_in[6];
    const float* beta  = (const float*)d_in[7];
    float* out = (float*)d_out;

    char* ws = (char*)d_ws;
    unsigned int* mbits = (unsigned int*)ws;
    unsigned short* h   = (unsigned short*)(ws + 0x080000);
    unsigned short* oh  = (unsigned short*)(ws + 0x880000);
    unsigned short* h2  = (unsigned short*)(ws + 0x080000);  // overlays h
    float2* ml          = (float2*)(ws + 0x280000);          // 256KB, in dead h region
    float* Opart        = (float*)(ws + 0x880000);           // overlays oh

    mask_kernel<<<16384, 256, 0, stream>>>(graph, mbits);
    proj_kernel<<<4096, 256, 0, stream>>>(x, Wh, h);
    gat_flash<2, 0><<<512, 256, 0, stream>>>(h, mbits, bh, 4, nullptr, nullptr, oh, nullptr);
    mix_gemm<<<256, 256, 0, stream>>>(oh, Wo, h2);
    gat_flash<1, 2><<<512, 256, 0, stream>>>(h2, mbits, bo, 1, nullptr, nullptr, Opart, ml);
    combine_ln<<<4096, 256, 0, stream>>>(Opart, ml, bo, gamma, beta, out);
}

// Round 13
// 205.952 us; speedup vs baseline: 1.3329x; 1.0670x over previous
//
#include <hip/hip_runtime.h>

#define NN 2048
#define PITCH 72   // u16 elems per LDS row (K tiles): 144B -> 16B-aligned rows
#define MPITCH 264 // u16 elems per LDS row (mix): 528B

typedef __attribute__((ext_vector_type(8))) _Float16 half8;  // 8 fp16 = 4 VGPRs (MFMA A/B frag)
typedef __attribute__((ext_vector_type(4))) float floatx4;   // MFMA C/D frag

static_assert(sizeof(half8) == 16, "");

#define MRINIT -3.0e38f

__device__ __forceinline__ unsigned short f2h(float f) {
    union { _Float16 h; unsigned short u; } v;
    v.h = (_Float16)f;  // RNE
    return v.u;
}
__device__ __forceinline__ float h2f(unsigned short u) {
    union { unsigned short u; _Float16 h; } v;
    v.u = u;
    return (float)v.h;
}
__device__ __forceinline__ unsigned int pk2h(float a, float b) {  // v_cvt_pkrtz_f16_f32
    union { __fp16 __attribute__((ext_vector_type(2))) h; unsigned int u; } v;
    v.h = __builtin_amdgcn_cvt_pkrtz(a, b);
    return v.u;
}
// barrier that does NOT drain vmcnt: LDS-visibility only; prefetch loads stay in flight.
__device__ __forceinline__ void barrier_lds_only() {
    __asm__ __volatile__("" ::: "memory");
    __builtin_amdgcn_s_waitcnt(0xC07F);  // vmcnt=63, expcnt=7, lgkmcnt=0
    __builtin_amdgcn_s_barrier();
    __asm__ __volatile__("" ::: "memory");
}

// ---------- mask = (graph + I) > 0, packed to bits ----------
__global__ __launch_bounds__(256) void mask_kernel(const int* __restrict__ graph,
                                                   unsigned int* __restrict__ mbits) {
    const int t = threadIdx.x;
    const int lane = t & 63;
    const int W = (blockIdx.x << 2) + (t >> 6);
    const int i = W >> 5;
    const int cb = W & 31;
    const int j = (cb << 6) + lane;
    const int g = graph[(size_t)i * NN + j];
    const unsigned long long bal = __ballot((g > 0) || (i == j));
    if (lane == 0)  mbits[(i << 6) + (cb << 1)]     = (unsigned int)bal;
    if (lane == 32) mbits[(i << 6) + (cb << 1) + 1] = (unsigned int)(bal >> 32);
}

// ---------- proj as MFMA GEMM: h[b,h,n,d] = sum_c x[b,n,c] * Wh[h,d,c] ----------
// 256 blocks (8 b x 32 n-tiles of 64); wave = head. A = x rows (fp16-staged),
// B[k=c][n=d] = Wh[h][d][c] -> row-major b128 reads (no transpose needed).
__global__ __launch_bounds__(256) void proj_gemm(const float* __restrict__ x,
                                                 const float* __restrict__ Wh,
                                                 unsigned short* __restrict__ hout) {
    __shared__ unsigned short xs[64 * PITCH];      // 9.2 KB  x tile [n][c] fp16
    __shared__ unsigned short wh[4 * 64 * PITCH];  // 36.9 KB Wh [h][d][c] fp16
    const int t = threadIdx.x;
    const int b = blockIdx.x >> 5;
    const int n0 = (blockIdx.x & 31) << 6;
    for (int i = t; i < 512; i += 256) {
        const int r = i >> 3, c8 = (i & 7) << 3;
        const float* xp = x + (((size_t)b * NN + n0 + r) << 6) + c8;
        const float4 f0 = *(const float4*)(xp);
        const float4 f1 = *(const float4*)(xp + 4);
        uint4 pk;
        pk.x = pk2h(f0.x, f0.y); pk.y = pk2h(f0.z, f0.w);
        pk.z = pk2h(f1.x, f1.y); pk.w = pk2h(f1.z, f1.w);
        *(uint4*)(&xs[r * PITCH + c8]) = pk;
    }
    for (int i = t; i < 2048; i += 256) {
        const int hd = i >> 3, c8 = (i & 7) << 3;
        const float* wp = Wh + ((size_t)hd << 6) + c8;
        const float4 f0 = *(const float4*)(wp);
        const float4 f1 = *(const float4*)(wp + 4);
        uint4 pk;
        pk.x = pk2h(f0.x, f0.y); pk.y = pk2h(f0.z, f0.w);
        pk.z = pk2h(f1.x, f1.y); pk.w = pk2h(f1.z, f1.w);
        *(uint4*)(&wh[hd * PITCH + c8]) = pk;
    }
    __syncthreads();
    const int wave = t >> 6;  // head
    const int m = t & 15;
    const int quad = (t >> 4) & 3;
    half8 bf0[4], bf1[4];
#pragma unroll
    for (int nt = 0; nt < 4; ++nt) {
        const int row = (wave << 6) + (nt << 4) + m;
        bf0[nt] = *(const half8*)(&wh[row * PITCH + (quad << 3)]);
        bf1[nt] = *(const half8*)(&wh[row * PITCH + 32 + (quad << 3)]);
    }
    floatx4 acc[4][4];  // [mt][nt]
#pragma unroll
    for (int mt = 0; mt < 4; ++mt)
#pragma unroll
        for (int nt = 0; nt < 4; ++nt) acc[mt][nt] = floatx4{0.f, 0.f, 0.f, 0.f};
#pragma unroll
    for (int mt = 0; mt < 4; ++mt) {
        const half8 a0 = *(const half8*)(&xs[((mt << 4) + m) * PITCH + (quad << 3)]);
        const half8 a1 = *(const half8*)(&xs[((mt << 4) + m) * PITCH + 32 + (quad << 3)]);
#pragma unroll
        for (int nt = 0; nt < 4; ++nt) {
            acc[mt][nt] = __builtin_amdgcn_mfma_f32_16x16x32_f16(a0, bf0[nt], acc[mt][nt], 0, 0, 0);
            acc[mt][nt] = __builtin_amdgcn_mfma_f32_16x16x32_f16(a1, bf1[nt], acc[mt][nt], 0, 0, 0);
        }
    }
    // D[row = 16mt + 4quad + reg][col = 16nt + m]
    unsigned short* hp = hout + ((((size_t)(b << 2) + wave) * NN + n0) << 6) + m;
#pragma unroll
    for (int mt = 0; mt < 4; ++mt)
#pragma unroll
        for (int reg = 0; reg < 4; ++reg)
#pragma unroll
            for (int nt = 0; nt < 4; ++nt)
                hp[(((mt << 4) + (quad << 2) + reg) << 6) + (nt << 4)] = f2h(acc[mt][nt][reg]);
}

// ---------- fused GAT layer (r9 core, rotation swizzles, Ps pitch 64) ----------
// OUTMODE 0: fp16 out, leaky fused. OUTMODE 1: fused leaky+LN fp32. OUTMODE 2: split-K
// partials (un-normalized O fp32 + per-row (m,l)); grid carries a split bit; 16 K-tiles.
template <int QG, int OUTMODE>
__global__ __launch_bounds__(256) void gat_flash(const unsigned short* __restrict__ Hm,
                                                 const unsigned int* __restrict__ mbits,
                                                 const float* __restrict__ bias,
                                                 const int bias_mod,
                                                 const float* __restrict__ gamma,
                                                 const float* __restrict__ beta,
                                                 void* __restrict__ OutP,
                                                 float2* __restrict__ mlP) {
    __shared__ unsigned short Ks[2][64 * PITCH];
    __shared__ unsigned short Kts[2][64 * PITCH];
    __shared__ unsigned short Ps[4 * QG * 16 * 64];  // pitch 64: rotation swizzle keeps floor

    const int t = threadIdx.x;
    const int wave = t >> 6;
    const int lane = t & 63;
    const int quad = lane >> 4;
    const int m = lane & 15;

    const int qtbits = (QG == 2) ? 4 : 5;
    const int bid = blockIdx.x;
    const int qt = bid & ((1 << qtbits) - 1);
    const int split = (OUTMODE == 2) ? ((bid >> qtbits) & 1) : 0;
    const int mat = bid >> (qtbits + ((OUTMODE == 2) ? 1 : 0));
    const int q0 = qt << ((QG == 2) ? 7 : 6);
    const int nkt = (OUTMODE == 2) ? 16 : 32;
    const int kt0 = split * nkt;

    const unsigned short* Hb = Hm + ((size_t)mat << 17);
    const int wbase = q0 + wave * (16 * QG);

    const _Float16 LOG2E = (_Float16)1.44269504f;
    half8 bq0[QG], bq1[QG];
    int gq[QG];
#pragma unroll
    for (int g = 0; g < QG; ++g) {
        gq[g] = wbase + (g << 4) + m;
        bq0[g] = *(const half8*)(Hb + (gq[g] << 6) + (quad << 3)) * LOG2E;
        bq1[g] = *(const half8*)(Hb + (gq[g] << 6) + 32 + (quad << 3)) * LOG2E;
    }

    const int boff = (mat % bias_mod) << 6;
    const float bv0 = bias[boff + m];
    const float bv1 = bias[boff + 16 + m];
    const float bv2 = bias[boff + 32 + m];
    const float bv3 = bias[boff + 48 + m];

    const int p = t >> 3;
    const int cc = t & 7;
    const int jch = p >> 2;
    const int jo = (p & 3) << 1;

    float mr[QG], lr[QG];
    floatx4 O[QG][4];
#pragma unroll
    for (int g = 0; g < QG; ++g) {
        mr[g] = MRINIT;
        lr[g] = 0.f;
#pragma unroll
        for (int nt = 0; nt < 4; ++nt) O[g][nt] = floatx4{0.f, 0.f, 0.f, 0.f};
    }

    const int msw = m & 7;
    int psb[QG];
#pragma unroll
    for (int g = 0; g < QG; ++g) psb[g] = (wave * QG + g) * 1024 + (m << 6);

    // ---- prefetch tile kt0 into registers ----
    const unsigned short* kg0 = Hb + (((kt0 << 6) + (p << 1)) << 6) + (cc << 3);
    half8 ra = *(const half8*)(kg0);
    half8 rb = *(const half8*)(kg0 + 64);

    for (int it = 0; it < nkt; ++it) {
        const int kt = kt0 + it;
        unsigned short* KS = Ks[it & 1];
        unsigned short* KT = Kts[it & 1];
        *(half8*)(&KS[(p << 1) * PITCH + (cc << 3)]) = ra;
        *(half8*)(&KS[((p << 1) + 1) * PITCH + (cc << 3)]) = rb;
        union { half8 v; unsigned int u[4]; } kaU, kbU;
        kaU.v = ra;
        kbU.v = rb;
#pragma unroll
        for (int c = 0; c < 4; ++c) {
            const unsigned int ua = kaU.u[c];
            const unsigned int ub = kbU.u[c];
            const unsigned int lo = __builtin_amdgcn_perm(ub, ua, 0x05040100);
            const unsigned int hi = __builtin_amdgcn_perm(ub, ua, 0x07060302);
            const int d0 = (cc << 3) + (c << 1);
            const int pos = (((jch + cc) & 7) << 3) + jo;  // rotation swizzle
            *(unsigned int*)(&KT[d0 * PITCH + pos]) = lo;
            *(unsigned int*)(&KT[(d0 + 1) * PITCH + pos]) = hi;
        }
        const int ktn = kt0 + ((it + 1) & (nkt - 1));
        const unsigned short* kgn = Hb + (((ktn << 6) + (p << 1)) << 6) + (cc << 3);
        ra = *(const half8*)(kgn);
        rb = *(const half8*)(kgn + 64);

        barrier_lds_only();

        floatx4 a[QG][4];
#pragma unroll
        for (int jt = 0; jt < 4; ++jt) {
            const half8 k0 = *(const half8*)(&KS[((jt << 4) + m) * PITCH + (quad << 3)]);
            const half8 k1 = *(const half8*)(&KS[((jt << 4) + m) * PITCH + 32 + (quad << 3)]);
#pragma unroll
            for (int g = 0; g < QG; ++g) {
                floatx4 z = {0.f, 0.f, 0.f, 0.f};
                z = __builtin_amdgcn_mfma_f32_16x16x32_f16(k0, bq0[g], z, 0, 0, 0);
                z = __builtin_amdgcn_mfma_f32_16x16x32_f16(k1, bq1[g], z, 0, 0, 0);
                a[g][jt] = z;
            }
        }

#pragma unroll
        for (int g = 0; g < QG; ++g) {
            const int mrow = gq[g] << 6;
            const unsigned int w0 = mbits[mrow + (kt << 1)];
            const unsigned int w1 = mbits[mrow + (kt << 1) + 1];

            float tmx = MRINIT;
#pragma unroll
            for (int jt = 0; jt < 4; ++jt) {
                const unsigned int wv = (jt < 2) ? w0 : w1;
                const unsigned int bits = (wv >> (((jt & 1) << 4) + (quad << 2))) & 0xFu;
#pragma unroll
                for (int reg = 0; reg < 4; ++reg) {
                    const float v = ((bits >> reg) & 1u) ? a[g][jt][reg] : MRINIT;
                    a[g][jt][reg] = v;
                    tmx = fmaxf(tmx, v);
                }
            }
            tmx = fmaxf(tmx, __shfl_xor(tmx, 16));
            tmx = fmaxf(tmx, __shfl_xor(tmx, 32));
            const float mnew = fmaxf(mr[g], tmx);
            const float alpha = __builtin_amdgcn_exp2f(mr[g] - mnew);
            const bool need = __any(mnew > mr[g]);

            float psum = 0.f;
#pragma unroll
            for (int jt = 0; jt < 4; ++jt) {
                const float p0 = __builtin_amdgcn_exp2f(a[g][jt][0] - mnew);
                const float p1 = __builtin_amdgcn_exp2f(a[g][jt][1] - mnew);
                const float p2 = __builtin_amdgcn_exp2f(a[g][jt][2] - mnew);
                const float p3 = __builtin_amdgcn_exp2f(a[g][jt][3] - mnew);
                psum += (p0 + p1) + (p2 + p3);
                const int ch = (jt << 1) + (quad >> 1);
                *(uint2*)(&Ps[psb[g] + (((ch + msw) & 7) << 3) + ((quad & 1) << 2)]) =
                    make_uint2(pk2h(p0, p1), pk2h(p2, p3));  // rotation swizzle
            }
            psum += __shfl_xor(psum, 16);
            psum += __shfl_xor(psum, 32);
            lr[g] = lr[g] * alpha + psum;
            mr[g] = mnew;

            if (need) {
                const float aO0 = __shfl(alpha, (quad << 2) + 0);
                const float aO1 = __shfl(alpha, (quad << 2) + 1);
                const float aO2 = __shfl(alpha, (quad << 2) + 2);
                const float aO3 = __shfl(alpha, (quad << 2) + 3);
#pragma unroll
                for (int nt = 0; nt < 4; ++nt) {
                    O[g][nt][0] *= aO0;
                    O[g][nt][1] *= aO1;
                    O[g][nt][2] *= aO2;
                    O[g][nt][3] *= aO3;
                }
            }
        }

        __builtin_amdgcn_wave_barrier();
        __asm__ __volatile__("" ::: "memory");

        half8 pa0[QG], pa1[QG];
#pragma unroll
        for (int g = 0; g < QG; ++g) {
            pa0[g] = *(const half8*)(&Ps[psb[g] + (((quad + msw) & 7) << 3)]);
            pa1[g] = *(const half8*)(&Ps[psb[g] + (((4 + quad + msw) & 7) << 3)]);
        }
#pragma unroll
        for (int nt = 0; nt < 4; ++nt) {
            const int d = (nt << 4) + m;
            const int sw = (d >> 3) & 7;
            const half8 v0 = *(const half8*)(&KT[d * PITCH + (((quad + sw) & 7) << 3)]);
            const half8 v1 = *(const half8*)(&KT[d * PITCH + (((4 + quad + sw) & 7) << 3)]);
#pragma unroll
            for (int g = 0; g < QG; ++g) {
                O[g][nt] = __builtin_amdgcn_mfma_f32_16x16x32_f16(pa0[g], v0, O[g][nt], 0, 0, 0);
                O[g][nt] = __builtin_amdgcn_mfma_f32_16x16x32_f16(pa1[g], v1, O[g][nt], 0, 0, 0);
            }
        }
    }

    // ---- epilogue ----
    if (OUTMODE == 2) {
        float* Ob = (float*)OutP +
                    ((((size_t)(split << 3) + mat) * NN + wbase + (quad << 2)) << 6) + m;
#pragma unroll
        for (int reg = 0; reg < 4; ++reg)
#pragma unroll
            for (int nt = 0; nt < 4; ++nt)
                Ob[(reg << 6) + (nt << 4)] = O[0][nt][reg];
        if (lane < 16)
            mlP[((size_t)(split << 3) + mat) * NN + wbase + m] = make_float2(mr[0], lr[0]);
        return;
    }

    float g0, g1, g2, g3, be0, be1, be2, be3;
    if (OUTMODE == 1) {
        g0 = gamma[m]; g1 = gamma[16 + m]; g2 = gamma[32 + m]; g3 = gamma[48 + m];
        be0 = beta[m]; be1 = beta[16 + m]; be2 = beta[32 + m]; be3 = beta[48 + m];
    }
#pragma unroll
    for (int g = 0; g < QG; ++g) {
        const float l0 = 1.f / __shfl(lr[g], (quad << 2) + 0);
        const float l1 = 1.f / __shfl(lr[g], (quad << 2) + 1);
        const float l2 = 1.f / __shfl(lr[g], (quad << 2) + 2);
        const float l3 = 1.f / __shfl(lr[g], (quad << 2) + 3);
        const size_t obase = (((size_t)mat * NN + wbase + (g << 4) + (quad << 2)) << 6) + m;
#pragma unroll
        for (int reg = 0; reg < 4; ++reg) {
            const float li = (reg == 0) ? l0 : (reg == 1) ? l1 : (reg == 2) ? l2 : l3;
            float z0 = O[g][0][reg] * li + bv0;
            float z1 = O[g][1][reg] * li + bv1;
            float z2 = O[g][2][reg] * li + bv2;
            float z3 = O[g][3][reg] * li + bv3;
            z0 = (z0 > 0.f) ? z0 : 0.2f * z0;
            z1 = (z1 > 0.f) ? z1 : 0.2f * z1;
            z2 = (z2 > 0.f) ? z2 : 0.2f * z2;
            z3 = (z3 > 0.f) ? z3 : 0.2f * z3;
            if (OUTMODE == 0) {
                unsigned short* op = (unsigned short*)OutP + obase + ((size_t)reg << 6);
                op[0] = f2h(z0); op[16] = f2h(z1); op[32] = f2h(z2); op[48] = f2h(z3);
            } else {
                float s = ((z0 + z1) + (z2 + z3));
                float sq = ((z0 * z0 + z1 * z1) + (z2 * z2 + z3 * z3));
#pragma unroll
                for (int off = 1; off < 16; off <<= 1) {
                    s += __shfl_xor(s, off);
                    sq += __shfl_xor(sq, off);
                }
                const float mu = s * 0.015625f;
                float var = sq * 0.015625f - mu * mu;
                var = fmaxf(var, 0.f);
                const float rstd = rsqrtf(var + 1e-5f);
                float* op = (float*)OutP + obase + ((size_t)reg << 6);
                op[0]  = (z0 - mu) * rstd * g0 + be0;
                op[16] = (z1 - mu) * rstd * g1 + be1;
                op[32] = (z2 - mu) * rstd * g2 + be2;
                op[48] = (z3 - mu) * rstd * g3 + be3;
            }
        }
    }
}

// ---------- mix as MFMA GEMM: h2[b,r,d] = sum_k z[b,r,k] * Wo[d,k] ----------
__global__ __launch_bounds__(256) void mix_gemm(const unsigned short* __restrict__ oh,
                                                const float* __restrict__ Wo,
                                                unsigned short* __restrict__ h2) {
    __shared__ unsigned short zs[64 * MPITCH];
    __shared__ unsigned short wsm[64 * MPITCH];
    const int t = threadIdx.x;
    const int b = blockIdx.x >> 5;
    const int n0 = (blockIdx.x & 31) << 6;
    for (int i = t; i < 2048; i += 256) {
        const int hh = i >> 9;
        const int r = (i >> 3) & 63;
        const int d8 = i & 7;
        const half8 v = *(const half8*)(oh + ((((size_t)b << 2) + hh) * NN + n0 + r) * 64 + (d8 << 3));
        *(half8*)(&zs[r * MPITCH + (hh << 6) + (d8 << 3)]) = v;
    }
    for (int i = t; i < 2048; i += 256) {
        const int d = i >> 5;
        const int k0 = (i & 31) << 3;
        const float4 f0 = *(const float4*)(Wo + (d << 8) + k0);
        const float4 f1 = *(const float4*)(Wo + (d << 8) + k0 + 4);
        uint4 pk;
        pk.x = pk2h(f0.x, f0.y);
        pk.y = pk2h(f0.z, f0.w);
        pk.z = pk2h(f1.x, f1.y);
        pk.w = pk2h(f1.z, f1.w);
        *(uint4*)(&wsm[d * MPITCH + k0]) = pk;
    }
    __syncthreads();
    const int wave = t >> 6;
    const int m = t & 15;
    const int quad = (t >> 4) & 3;
    const int ar = (wave << 4) + m;
    floatx4 acc[4] = {{0.f, 0.f, 0.f, 0.f}, {0.f, 0.f, 0.f, 0.f},
                      {0.f, 0.f, 0.f, 0.f}, {0.f, 0.f, 0.f, 0.f}};
#pragma unroll
    for (int chunk = 0; chunk < 8; ++chunk) {
        const int k0 = chunk << 5;
        const half8 af = *(const half8*)(&zs[ar * MPITCH + k0 + (quad << 3)]);
#pragma unroll
        for (int nt = 0; nt < 4; ++nt) {
            const half8 bf = *(const half8*)(&wsm[((nt << 4) + m) * MPITCH + k0 + (quad << 3)]);
            acc[nt] = __builtin_amdgcn_mfma_f32_16x16x32_f16(af, bf, acc[nt], 0, 0, 0);
        }
    }
    unsigned short* hp = h2 + (((size_t)b * NN + n0 + (wave << 4) + (quad << 2)) << 6) + m;
#pragma unroll
    for (int reg = 0; reg < 4; ++reg)
#pragma unroll
        for (int nt = 0; nt < 4; ++nt)
            hp[(reg << 6) + (nt << 4)] = f2h(acc[nt][reg]);
}

// ---------- combine split-K partials + bias + leaky + LayerNorm (fp32 out) ----------
__global__ __launch_bounds__(256) void combine_ln(const float* __restrict__ Opart,
                                                  const float2* __restrict__ ml,
                                                  const float* __restrict__ bo,
                                                  const float* __restrict__ gamma,
                                                  const float* __restrict__ beta,
                                                  float* __restrict__ out) {
    const int t = threadIdx.x;
    const int lane = t & 63;
    const int widx = (blockIdx.x << 2) + (t >> 6);
    const size_t r0 = (size_t)widx;
    const float2 s0 = ml[r0];
    const float2 s1 = ml[(size_t)(NN * 8) + r0];
    const float mm = fmaxf(s0.x, s1.x);
    const float c0 = __builtin_amdgcn_exp2f(s0.x - mm);
    const float c1 = __builtin_amdgcn_exp2f(s1.x - mm);
    const float l = s0.y * c0 + s1.y * c1;
    const float o0 = Opart[(r0 << 6) + lane];
    const float o1 = Opart[(((size_t)(NN * 8) + r0) << 6) + lane];
    float v = (o0 * c0 + o1 * c1) / l + bo[lane];
    v = (v > 0.f) ? v : 0.2f * v;
    float s = v;
    float sq = v * v;
#pragma unroll
    for (int off = 1; off < 64; off <<= 1) {
        s += __shfl_xor(s, off);
        sq += __shfl_xor(sq, off);
    }
    const float mu = s * 0.015625f;
    float var = sq * 0.015625f - mu * mu;
    var = fmaxf(var, 0.f);
    const float rstd = rsqrtf(var + 1e-5f);
    out[(r0 << 6) + lane] = (v - mu) * rstd * gamma[lane] + beta[lane];
}

extern "C" void kernel_launch(void* const* d_in, const int* in_sizes, int n_in,
                              void* d_out, int out_size, void* d_ws, size_t ws_size,
                              hipStream_t stream) {
    const float* x     = (const float*)d_in[0];
    const int*   graph = (const int*)d_in[1];
    const float* Wh    = (const float*)d_in[2];
    const float* bh    = (const float*)d_in[3];
    const float* Wo    = (const float*)d_in[4];
    const float* bo    = (const float*)d_in[5];
    const float* gamma = (const float*)d_in[6];
    const float* beta  = (const float*)d_in[7];
    float* out = (float*)d_out;

    char* ws = (char*)d_ws;
    unsigned int* mbits = (unsigned int*)ws;
    unsigned short* h   = (unsigned short*)(ws + 0x080000);
    unsigned short* oh  = (unsigned short*)(ws + 0x880000);
    unsigned short* h2  = (unsigned short*)(ws + 0x080000);  // overlays h
    float2* ml          = (float2*)(ws + 0x280000);          // 256KB, in dead h region
    float* Opart        = (float*)(ws + 0x880000);           // overlays oh

    mask_kernel<<<16384, 256, 0, stream>>>(graph, mbits);
    proj_gemm<<<256, 256, 0, stream>>>(x, Wh, h);
    gat_flash<2, 0><<<512, 256, 0, stream>>>(h, mbits, bh, 4, nullptr, nullptr, oh, nullptr);
    mix_gemm<<<256, 256, 0, stream>>>(oh, Wo, h2);
    gat_flash<1, 2><<<512, 256, 0, stream>>>(h2, mbits, bo, 1, nullptr, nullptr, Opart, ml);
    combine_ln<<<4096, 256, 0, stream>>>(Opart, ml, bo, gamma, beta, out);
}

// Round 14
// 198.858 us; speedup vs baseline: 1.3804x; 1.0357x over previous
//
#include <hip/hip_runtime.h>

#define NN 2048
#define PITCH 72   // u16 elems per LDS row (K tiles): 144B -> 16B-aligned rows
#define MPITCH 264 // u16 elems per LDS row (mix): 528B

typedef __attribute__((ext_vector_type(8))) _Float16 half8;  // 8 fp16 = 4 VGPRs (MFMA A/B frag)
typedef __attribute__((ext_vector_type(4))) float floatx4;   // MFMA C/D frag

static_assert(sizeof(half8) == 16, "");

#define MRINIT -3.0e38f

__device__ __forceinline__ unsigned short f2h(float f) {
    union { _Float16 h; unsigned short u; } v;
    v.h = (_Float16)f;  // RNE
    return v.u;
}
__device__ __forceinline__ float h2f(unsigned short u) {
    union { unsigned short u; _Float16 h; } v;
    v.u = u;
    return (float)v.h;
}
__device__ __forceinline__ unsigned int pk2h(float a, float b) {  // v_cvt_pkrtz_f16_f32
    union { __fp16 __attribute__((ext_vector_type(2))) h; unsigned int u; } v;
    v.h = __builtin_amdgcn_cvt_pkrtz(a, b);
    return v.u;
}
// barrier that does NOT drain vmcnt: LDS-visibility only; prefetch loads stay in flight.
__device__ __forceinline__ void barrier_lds_only() {
    __asm__ __volatile__("" ::: "memory");
    __builtin_amdgcn_s_waitcnt(0xC07F);  // vmcnt=63, expcnt=7, lgkmcnt=0
    __builtin_amdgcn_s_barrier();
    __asm__ __volatile__("" ::: "memory");
}

// ---------- mask = (graph + I) > 0, packed to bits ----------
__global__ __launch_bounds__(256) void mask_kernel(const int* __restrict__ graph,
                                                   unsigned int* __restrict__ mbits) {
    const int t = threadIdx.x;
    const int lane = t & 63;
    const int W = (blockIdx.x << 2) + (t >> 6);
    const int i = W >> 5;
    const int cb = W & 31;
    const int j = (cb << 6) + lane;
    const int g = graph[(size_t)i * NN + j];
    const unsigned long long bal = __ballot((g > 0) || (i == j));
    if (lane == 0)  mbits[(i << 6) + (cb << 1)]     = (unsigned int)bal;
    if (lane == 32) mbits[(i << 6) + (cb << 1) + 1] = (unsigned int)(bal >> 32);
}

// ---------- proj as MFMA GEMM: h[b,h,n,d] = sum_c x[b,n,c] * Wh[h,d,c] ----------
__global__ __launch_bounds__(256) void proj_gemm(const float* __restrict__ x,
                                                 const float* __restrict__ Wh,
                                                 unsigned short* __restrict__ hout) {
    __shared__ unsigned short xs[64 * PITCH];
    __shared__ unsigned short wh[4 * 64 * PITCH];
    const int t = threadIdx.x;
    const int b = blockIdx.x >> 5;
    const int n0 = (blockIdx.x & 31) << 6;
    for (int i = t; i < 512; i += 256) {
        const int r = i >> 3, c8 = (i & 7) << 3;
        const float* xp = x + (((size_t)b * NN + n0 + r) << 6) + c8;
        const float4 f0 = *(const float4*)(xp);
        const float4 f1 = *(const float4*)(xp + 4);
        uint4 pk;
        pk.x = pk2h(f0.x, f0.y); pk.y = pk2h(f0.z, f0.w);
        pk.z = pk2h(f1.x, f1.y); pk.w = pk2h(f1.z, f1.w);
        *(uint4*)(&xs[r * PITCH + c8]) = pk;
    }
    for (int i = t; i < 2048; i += 256) {
        const int hd = i >> 3, c8 = (i & 7) << 3;
        const float* wp = Wh + ((size_t)hd << 6) + c8;
        const float4 f0 = *(const float4*)(wp);
        const float4 f1 = *(const float4*)(wp + 4);
        uint4 pk;
        pk.x = pk2h(f0.x, f0.y); pk.y = pk2h(f0.z, f0.w);
        pk.z = pk2h(f1.x, f1.y); pk.w = pk2h(f1.z, f1.w);
        *(uint4*)(&wh[hd * PITCH + c8]) = pk;
    }
    __syncthreads();
    const int wave = t >> 6;  // head
    const int m = t & 15;
    const int quad = (t >> 4) & 3;
    half8 bf0[4], bf1[4];
#pragma unroll
    for (int nt = 0; nt < 4; ++nt) {
        const int row = (wave << 6) + (nt << 4) + m;
        bf0[nt] = *(const half8*)(&wh[row * PITCH + (quad << 3)]);
        bf1[nt] = *(const half8*)(&wh[row * PITCH + 32 + (quad << 3)]);
    }
    floatx4 acc[4][4];
#pragma unroll
    for (int mt = 0; mt < 4; ++mt)
#pragma unroll
        for (int nt = 0; nt < 4; ++nt) acc[mt][nt] = floatx4{0.f, 0.f, 0.f, 0.f};
#pragma unroll
    for (int mt = 0; mt < 4; ++mt) {
        const half8 a0 = *(const half8*)(&xs[((mt << 4) + m) * PITCH + (quad << 3)]);
        const half8 a1 = *(const half8*)(&xs[((mt << 4) + m) * PITCH + 32 + (quad << 3)]);
#pragma unroll
        for (int nt = 0; nt < 4; ++nt) {
            acc[mt][nt] = __builtin_amdgcn_mfma_f32_16x16x32_f16(a0, bf0[nt], acc[mt][nt], 0, 0, 0);
            acc[mt][nt] = __builtin_amdgcn_mfma_f32_16x16x32_f16(a1, bf1[nt], acc[mt][nt], 0, 0, 0);
        }
    }
    unsigned short* hp = hout + ((((size_t)(b << 2) + wave) * NN + n0) << 6) + m;
#pragma unroll
    for (int mt = 0; mt < 4; ++mt)
#pragma unroll
        for (int reg = 0; reg < 4; ++reg)
#pragma unroll
            for (int nt = 0; nt < 4; ++nt)
                hp[(((mt << 4) + (quad << 2) + reg) << 6) + (nt << 4)] = f2h(acc[mt][nt][reg]);
}

// ---------- fused GAT layer (rotation swizzles, O^T accumulation) ----------
// PV computes O^T = V^T * P^T via operand swap (identical LDS reads); lane's C column
// = its own q-row -> alpha rescale and 1/l are per-lane scalars (no broadcast shuffles).
// OUTMODE 0: fp16 out, leaky fused. OUTMODE 2: split-K fp16 partials + per-row (m,l).
template <int QG, int OUTMODE, int NSPLIT>
__global__ __launch_bounds__(256) void gat_flash(const unsigned short* __restrict__ Hm,
                                                 const unsigned int* __restrict__ mbits,
                                                 const float* __restrict__ bias,
                                                 const int bias_mod,
                                                 void* __restrict__ OutP,
                                                 float2* __restrict__ mlP) {
    __shared__ unsigned short Ks[2][64 * PITCH];
    __shared__ unsigned short Kts[2][64 * PITCH];
    __shared__ unsigned short Ps[4 * QG * 16 * 64];

    const int t = threadIdx.x;
    const int wave = t >> 6;
    const int lane = t & 63;
    const int quad = lane >> 4;
    const int m = lane & 15;

    const int qtbits = 4;  // QG==2: 128 q-rows/block
    const int sbits = (NSPLIT == 4) ? 2 : (NSPLIT == 2) ? 1 : 0;
    const int bid = blockIdx.x;
    const int qt = bid & ((1 << qtbits) - 1);
    const int split = (bid >> qtbits) & (NSPLIT - 1);
    const int mat = bid >> (qtbits + sbits);
    const int q0 = qt << 7;
    const int nkt = 32 / NSPLIT;
    const int kt0 = split * nkt;

    const unsigned short* Hb = Hm + ((size_t)mat << 17);
    const int wbase = q0 + wave * (16 * QG);

    const _Float16 LOG2E = (_Float16)1.44269504f;
    half8 bq0[QG], bq1[QG];
    int gq[QG];
#pragma unroll
    for (int g = 0; g < QG; ++g) {
        gq[g] = wbase + (g << 4) + m;
        bq0[g] = *(const half8*)(Hb + (gq[g] << 6) + (quad << 3)) * LOG2E;
        bq1[g] = *(const half8*)(Hb + (gq[g] << 6) + 32 + (quad << 3)) * LOG2E;
    }

    const int p = t >> 3;
    const int cc = t & 7;
    const int jch = p >> 2;
    const int jo = (p & 3) << 1;

    float mr[QG], lr[QG];
    floatx4 O[QG][4];
#pragma unroll
    for (int g = 0; g < QG; ++g) {
        mr[g] = MRINIT;
        lr[g] = 0.f;
#pragma unroll
        for (int nt = 0; nt < 4; ++nt) O[g][nt] = floatx4{0.f, 0.f, 0.f, 0.f};
    }

    const int msw = m & 7;
    int psb[QG];
#pragma unroll
    for (int g = 0; g < QG; ++g) psb[g] = (wave * QG + g) * 1024 + (m << 6);

    const unsigned short* kg0 = Hb + (((kt0 << 6) + (p << 1)) << 6) + (cc << 3);
    half8 ra = *(const half8*)(kg0);
    half8 rb = *(const half8*)(kg0 + 64);

    for (int it = 0; it < nkt; ++it) {
        const int kt = kt0 + it;
        unsigned short* KS = Ks[it & 1];
        unsigned short* KT = Kts[it & 1];
        *(half8*)(&KS[(p << 1) * PITCH + (cc << 3)]) = ra;
        *(half8*)(&KS[((p << 1) + 1) * PITCH + (cc << 3)]) = rb;
        union { half8 v; unsigned int u[4]; } kaU, kbU;
        kaU.v = ra;
        kbU.v = rb;
#pragma unroll
        for (int c = 0; c < 4; ++c) {
            const unsigned int ua = kaU.u[c];
            const unsigned int ub = kbU.u[c];
            const unsigned int lo = __builtin_amdgcn_perm(ub, ua, 0x05040100);
            const unsigned int hi = __builtin_amdgcn_perm(ub, ua, 0x07060302);
            const int d0 = (cc << 3) + (c << 1);
            const int pos = (((jch + cc) & 7) << 3) + jo;  // rotation swizzle
            *(unsigned int*)(&KT[d0 * PITCH + pos]) = lo;
            *(unsigned int*)(&KT[(d0 + 1) * PITCH + pos]) = hi;
        }
        const int ktn = kt0 + ((it + 1) & (nkt - 1));
        const unsigned short* kgn = Hb + (((ktn << 6) + (p << 1)) << 6) + (cc << 3);
        ra = *(const half8*)(kgn);
        rb = *(const half8*)(kgn + 64);

        barrier_lds_only();

        // ---- S^T = K * Q^T : A = K rows from LDS, shared across groups ----
        floatx4 a[QG][4];
#pragma unroll
        for (int jt = 0; jt < 4; ++jt) {
            const half8 k0 = *(const half8*)(&KS[((jt << 4) + m) * PITCH + (quad << 3)]);
            const half8 k1 = *(const half8*)(&KS[((jt << 4) + m) * PITCH + 32 + (quad << 3)]);
#pragma unroll
            for (int g = 0; g < QG; ++g) {
                floatx4 z = {0.f, 0.f, 0.f, 0.f};
                z = __builtin_amdgcn_mfma_f32_16x16x32_f16(k0, bq0[g], z, 0, 0, 0);
                z = __builtin_amdgcn_mfma_f32_16x16x32_f16(k1, bq1[g], z, 0, 0, 0);
                a[g][jt] = z;
            }
        }

        // ---- per group: mask, online softmax, Ps write, O rescale (per-lane alpha) ----
#pragma unroll
        for (int g = 0; g < QG; ++g) {
            const int mrow = gq[g] << 6;
            const unsigned int w0 = mbits[mrow + (kt << 1)];
            const unsigned int w1 = mbits[mrow + (kt << 1) + 1];

            float tmx = MRINIT;
#pragma unroll
            for (int jt = 0; jt < 4; ++jt) {
                const unsigned int wv = (jt < 2) ? w0 : w1;
                const unsigned int bits = (wv >> (((jt & 1) << 4) + (quad << 2))) & 0xFu;
#pragma unroll
                for (int reg = 0; reg < 4; ++reg) {
                    const float v = ((bits >> reg) & 1u) ? a[g][jt][reg] : MRINIT;
                    a[g][jt][reg] = v;
                    tmx = fmaxf(tmx, v);
                }
            }
            tmx = fmaxf(tmx, __shfl_xor(tmx, 16));
            tmx = fmaxf(tmx, __shfl_xor(tmx, 32));
            const float mnew = fmaxf(mr[g], tmx);
            const float alpha = __builtin_amdgcn_exp2f(mr[g] - mnew);
            const bool need = __any(mnew > mr[g]);

            float psum = 0.f;
#pragma unroll
            for (int jt = 0; jt < 4; ++jt) {
                const float p0 = __builtin_amdgcn_exp2f(a[g][jt][0] - mnew);
                const float p1 = __builtin_amdgcn_exp2f(a[g][jt][1] - mnew);
                const float p2 = __builtin_amdgcn_exp2f(a[g][jt][2] - mnew);
                const float p3 = __builtin_amdgcn_exp2f(a[g][jt][3] - mnew);
                psum += (p0 + p1) + (p2 + p3);
                const int ch = (jt << 1) + (quad >> 1);
                *(uint2*)(&Ps[psb[g] + (((ch + msw) & 7) << 3) + ((quad & 1) << 2)]) =
                    make_uint2(pk2h(p0, p1), pk2h(p2, p3));
            }
            psum += __shfl_xor(psum, 16);
            psum += __shfl_xor(psum, 32);
            lr[g] = lr[g] * alpha + psum;
            mr[g] = mnew;

            if (need) {
#pragma unroll
                for (int nt = 0; nt < 4; ++nt) {
                    O[g][nt][0] *= alpha;  // O^T: lane's column = its own q-row
                    O[g][nt][1] *= alpha;
                    O[g][nt][2] *= alpha;
                    O[g][nt][3] *= alpha;
                }
            }
        }

        __builtin_amdgcn_wave_barrier();
        __asm__ __volatile__("" ::: "memory");

        // ---- O^T += V^T * P^T : A = KT rows, B = Ps rows (identical reads, swapped roles) ----
        half8 pa0[QG], pa1[QG];
#pragma unroll
        for (int g = 0; g < QG; ++g) {
            pa0[g] = *(const half8*)(&Ps[psb[g] + (((quad + msw) & 7) << 3)]);
            pa1[g] = *(const half8*)(&Ps[psb[g] + (((4 + quad + msw) & 7) << 3)]);
        }
#pragma unroll
        for (int nt = 0; nt < 4; ++nt) {
            const int d = (nt << 4) + m;
            const int sw = (d >> 3) & 7;
            const half8 v0 = *(const half8*)(&KT[d * PITCH + (((quad + sw) & 7) << 3)]);
            const half8 v1 = *(const half8*)(&KT[d * PITCH + (((4 + quad + sw) & 7) << 3)]);
#pragma unroll
            for (int g = 0; g < QG; ++g) {
                O[g][nt] = __builtin_amdgcn_mfma_f32_16x16x32_f16(v0, pa0[g], O[g][nt], 0, 0, 0);
                O[g][nt] = __builtin_amdgcn_mfma_f32_16x16x32_f16(v1, pa1[g], O[g][nt], 0, 0, 0);
            }
        }
    }

    // ---- epilogue (O^T: lane holds q-row gq[g], d = 16nt + 4quad + reg) ----
    if (OUTMODE == 2) {
        unsigned short* Op = (unsigned short*)OutP;
        const size_t pbase = ((size_t)(split << 3) + mat) * NN;
#pragma unroll
        for (int g = 0; g < QG; ++g) {
            unsigned short* Ob = Op + ((pbase + gq[g]) << 6) + (quad << 2);
#pragma unroll
            for (int nt = 0; nt < 4; ++nt)
                *(uint2*)(Ob + (nt << 4)) = make_uint2(pk2h(O[g][nt][0], O[g][nt][1]),
                                                       pk2h(O[g][nt][2], O[g][nt][3]));
        }
        if (lane < 16) {
#pragma unroll
            for (int g = 0; g < QG; ++g)
                mlP[pbase + wbase + (g << 4) + m] = make_float2(mr[g], lr[g]);
        }
        return;
    }

    // OUTMODE 0: normalize, +bias, leaky, fp16 store
    const int boff = (mat % bias_mod) << 6;
    float4 bb[4];
#pragma unroll
    for (int nt = 0; nt < 4; ++nt)
        bb[nt] = *(const float4*)(bias + boff + (nt << 4) + (quad << 2));
#pragma unroll
    for (int g = 0; g < QG; ++g) {
        const float li = 1.f / lr[g];
        unsigned short* op = (unsigned short*)OutP + (((size_t)mat * NN + gq[g]) << 6) + (quad << 2);
#pragma unroll
        for (int nt = 0; nt < 4; ++nt) {
            float z0 = O[g][nt][0] * li + bb[nt].x;
            float z1 = O[g][nt][1] * li + bb[nt].y;
            float z2 = O[g][nt][2] * li + bb[nt].z;
            float z3 = O[g][nt][3] * li + bb[nt].w;
            z0 = (z0 > 0.f) ? z0 : 0.2f * z0;
            z1 = (z1 > 0.f) ? z1 : 0.2f * z1;
            z2 = (z2 > 0.f) ? z2 : 0.2f * z2;
            z3 = (z3 > 0.f) ? z3 : 0.2f * z3;
            *(uint2*)(op + (nt << 4)) = make_uint2(pk2h(z0, z1), pk2h(z2, z3));
        }
    }
}

// ---------- mix as MFMA GEMM: h2[b,r,d] = sum_k z[b,r,k] * Wo[d,k] ----------
__global__ __launch_bounds__(256) void mix_gemm(const unsigned short* __restrict__ oh,
                                                const float* __restrict__ Wo,
                                                unsigned short* __restrict__ h2) {
    __shared__ unsigned short zs[64 * MPITCH];
    __shared__ unsigned short wsm[64 * MPITCH];
    const int t = threadIdx.x;
    const int b = blockIdx.x >> 5;
    const int n0 = (blockIdx.x & 31) << 6;
    for (int i = t; i < 2048; i += 256) {
        const int hh = i >> 9;
        const int r = (i >> 3) & 63;
        const int d8 = i & 7;
        const half8 v = *(const half8*)(oh + ((((size_t)b << 2) + hh) * NN + n0 + r) * 64 + (d8 << 3));
        *(half8*)(&zs[r * MPITCH + (hh << 6) + (d8 << 3)]) = v;
    }
    for (int i = t; i < 2048; i += 256) {
        const int d = i >> 5;
        const int k0 = (i & 31) << 3;
        const float4 f0 = *(const float4*)(Wo + (d << 8) + k0);
        const float4 f1 = *(const float4*)(Wo + (d << 8) + k0 + 4);
        uint4 pk;
        pk.x = pk2h(f0.x, f0.y);
        pk.y = pk2h(f0.z, f0.w);
        pk.z = pk2h(f1.x, f1.y);
        pk.w = pk2h(f1.z, f1.w);
        *(uint4*)(&wsm[d * MPITCH + k0]) = pk;
    }
    __syncthreads();
    const int wave = t >> 6;
    const int m = t & 15;
    const int quad = (t >> 4) & 3;
    const int ar = (wave << 4) + m;
    floatx4 acc[4] = {{0.f, 0.f, 0.f, 0.f}, {0.f, 0.f, 0.f, 0.f},
                      {0.f, 0.f, 0.f, 0.f}, {0.f, 0.f, 0.f, 0.f}};
#pragma unroll
    for (int chunk = 0; chunk < 8; ++chunk) {
        const int k0 = chunk << 5;
        const half8 af = *(const half8*)(&zs[ar * MPITCH + k0 + (quad << 3)]);
#pragma unroll
        for (int nt = 0; nt < 4; ++nt) {
            const half8 bf = *(const half8*)(&wsm[((nt << 4) + m) * MPITCH + k0 + (quad << 3)]);
            acc[nt] = __builtin_amdgcn_mfma_f32_16x16x32_f16(af, bf, acc[nt], 0, 0, 0);
        }
    }
    unsigned short* hp = h2 + (((size_t)b * NN + n0 + (wave << 4) + (quad << 2)) << 6) + m;
#pragma unroll
    for (int reg = 0; reg < 4; ++reg)
#pragma unroll
        for (int nt = 0; nt < 4; ++nt)
            hp[(reg << 6) + (nt << 4)] = f2h(acc[nt][reg]);
}

// ---------- combine 4 split-K partials + bias + leaky + LayerNorm (fp32 out) ----------
__global__ __launch_bounds__(256) void combine_ln(const unsigned short* __restrict__ Opart,
                                                  const float2* __restrict__ ml,
                                                  const float* __restrict__ bo,
                                                  const float* __restrict__ gamma,
                                                  const float* __restrict__ beta,
                                                  float* __restrict__ out) {
    const int t = threadIdx.x;
    const int lane = t & 63;
    const size_t r0 = (size_t)((blockIdx.x << 2) + (t >> 6));  // mat*2048 + row
    float2 sv[4];
    float mm = MRINIT;
#pragma unroll
    for (int s = 0; s < 4; ++s) {
        sv[s] = ml[(size_t)(NN * 8) * s + r0];
        mm = fmaxf(mm, sv[s].x);
    }
    float l = 0.f, osum = 0.f;
#pragma unroll
    for (int s = 0; s < 4; ++s) {
        const float c = __builtin_amdgcn_exp2f(sv[s].x - mm);
        l += sv[s].y * c;
        osum += h2f(Opart[(((size_t)(NN * 8) * s + r0) << 6) + lane]) * c;
    }
    float v = osum / l + bo[lane];
    v = (v > 0.f) ? v : 0.2f * v;
    float s = v;
    float sq = v * v;
#pragma unroll
    for (int off = 1; off < 64; off <<= 1) {
        s += __shfl_xor(s, off);
        sq += __shfl_xor(sq, off);
    }
    const float mu = s * 0.015625f;
    float var = sq * 0.015625f - mu * mu;
    var = fmaxf(var, 0.f);
    const float rstd = rsqrtf(var + 1e-5f);
    out[(r0 << 6) + lane] = (v - mu) * rstd * gamma[lane] + beta[lane];
}

extern "C" void kernel_launch(void* const* d_in, const int* in_sizes, int n_in,
                              void* d_out, int out_size, void* d_ws, size_t ws_size,
                              hipStream_t stream) {
    const float* x     = (const float*)d_in[0];
    const int*   graph = (const int*)d_in[1];
    const float* Wh    = (const float*)d_in[2];
    const float* bh    = (const float*)d_in[3];
    const float* Wo    = (const float*)d_in[4];
    const float* bo    = (const float*)d_in[5];
    const float* gamma = (const float*)d_in[6];
    const float* beta  = (const float*)d_in[7];
    float* out = (float*)d_out;

    // ---- workspace layout (16.5 MB, with reuse) ----
    // [0, 0.5M):     mbits
    // [0.5M, 8.5M):  h fp16 (dead after gat1) -> h2 overlays [0.5M, 2.5M); ml [2.5M, 3M)
    // [8.5M, 16.5M): oh fp16 (dead after mix) -> Opart fp16 overlays (8MB: 4 splits x 8 x 2048 x 64)
    char* ws = (char*)d_ws;
    unsigned int* mbits   = (unsigned int*)ws;
    unsigned short* h     = (unsigned short*)(ws + 0x080000);
    unsigned short* oh    = (unsigned short*)(ws + 0x880000);
    unsigned short* h2    = (unsigned short*)(ws + 0x080000);  // overlays h
    float2* ml            = (float2*)(ws + 0x280000);          // 512KB, in dead h region
    unsigned short* Opart = (unsigned short*)(ws + 0x880000);  // overlays oh

    mask_kernel<<<16384, 256, 0, stream>>>(graph, mbits);
    proj_gemm<<<256, 256, 0, stream>>>(x, Wh, h);
    gat_flash<2, 0, 1><<<512, 256, 0, stream>>>(h, mbits, bh, 4, oh, nullptr);      // layer 1
    mix_gemm<<<256, 256, 0, stream>>>(oh, Wo, h2);
    gat_flash<2, 2, 4><<<512, 256, 0, stream>>>(h2, mbits, bo, 1, Opart, ml);       // layer 2 partials
    combine_ln<<<4096, 256, 0, stream>>>(Opart, ml, bo, gamma, beta, out);
}